// Round 3
// baseline (886.067 us; speedup 1.0000x reference)
//
#include <hip/hip_runtime.h>

// Problem constants (fixed by the reference).
#define NNODES 100000
#define NEDGES 800000
#define DIN    128
#define HID    64
#define EMB    32
#define NIDX   50000
#define BN_EPS 1e-5f

// ---------------------------------------------------------------------------
// CSR build: histogram -> block scan -> scatter. Rebuilt every call (ws is
// re-poisoned). Edges packed as int2{col, val_bits}.
// ---------------------------------------------------------------------------

__global__ void hist_k(const int* __restrict__ rows, int* __restrict__ cnt, int E) {
    int e = blockIdx.x * 256 + threadIdx.x;
    if (e < E) atomicAdd(&cnt[rows[e]], 1);
}

__global__ void scan1_k(const int* __restrict__ cnt, int* __restrict__ part, int n) {
    __shared__ int s[256];
    int i = blockIdx.x * 256 + threadIdx.x;
    s[threadIdx.x] = (i < n) ? cnt[i] : 0;
    __syncthreads();
    for (int off = 128; off > 0; off >>= 1) {
        if (threadIdx.x < off) s[threadIdx.x] += s[threadIdx.x + off];
        __syncthreads();
    }
    if (threadIdx.x == 0) part[blockIdx.x] = s[0];
}

__global__ void scan2_k(int* part, int nb) {
    __shared__ int s[512];
    int t = threadIdx.x;
    int v = (t < nb) ? part[t] : 0;
    s[t] = v;
    __syncthreads();
    for (int off = 1; off < 512; off <<= 1) {
        int a = (t >= off) ? s[t - off] : 0;
        __syncthreads();
        s[t] += a;
        __syncthreads();
    }
    if (t < nb) part[t] = s[t] - v;   // exclusive prefix of block sums
}

__global__ void scan3_k(const int* __restrict__ cnt, const int* __restrict__ part,
                        int* __restrict__ rowptr, int* __restrict__ cursor, int n, int E) {
    __shared__ int s[256];
    int t = threadIdx.x;
    int i = blockIdx.x * 256 + t;
    int v = (i < n) ? cnt[i] : 0;
    s[t] = v;
    __syncthreads();
    for (int off = 1; off < 256; off <<= 1) {
        int a = (t >= off) ? s[t - off] : 0;
        __syncthreads();
        s[t] += a;
        __syncthreads();
    }
    if (i < n) {
        int ex = part[blockIdx.x] + s[t] - v;   // exclusive
        rowptr[i] = ex;
        cursor[i] = ex;
    }
    if (i == 0) rowptr[n] = E;
}

__global__ void scatter_k(const int* __restrict__ rows, const int* __restrict__ cols,
                          const float* __restrict__ vals, int* __restrict__ cursor,
                          int2* __restrict__ cs, int E) {
    int e = blockIdx.x * 256 + threadIdx.x;
    if (e < E) {
        int r = rows[e];
        int p = atomicAdd(&cursor[r], 1);
        cs[p] = make_int2(cols[e], __float_as_int(vals[e]));
    }
}

// ---------------------------------------------------------------------------
// Fused dual GEMM: Hn = act(X) @ Wn (+biases), Hg = act(X) @ Wg (+bias).
// act = optional per-column BN affine + ReLU applied while staging X in LDS.
//
// BR=128 rows/block, 256 threads, RPT rows x 4 cols per thread.
// K staged in BK=64 chunks: LDS = 128*68*4 = 34.8 KB -> 4 blocks/CU
// (round-2's full-K 67.6 KB tile capped at 2 blocks/CU, occupancy 16%).
// Inner loop walks k in 4s: RPT ds_read_b128 + 4 W float4 loads per 256 FMAs
// -> LDS pipe 192 cyc vs VALU 512 cyc per wave-chunk (round-2's scalar
// ds_read_b32 pattern was 93 vs 128 - near-saturated LDS pipe).
// __launch_bounds__(256,4): 4 waves/SIMD -> VGPR cap 128 (acc 64 + w 16 fits).
// ---------------------------------------------------------------------------

template <int K, int HOUT, bool AFF>
__global__ __launch_bounds__(256, 4) void gemm2_k(
    const float* __restrict__ X,
    const float* __restrict__ Wn, const float* __restrict__ Wg,   // (K, HOUT) row-major
    const float* __restrict__ bnA, const float* __restrict__ bnB, // optional biases, n-side
    const float* __restrict__ bgA,                                // optional bias, g-side
    const float* __restrict__ scale, const float* __restrict__ shift, // AFF: per-k affine
    float* __restrict__ Hn, float* __restrict__ Hg, int n)
{
    constexpr int BR   = 128;
    constexpr int BK   = (K > 64) ? 64 : K;   // K-chunk staged in LDS
    constexpr int NKCH = K / BK;
    constexpr int LDK  = BK + 4;              // 16B-aligned pad
    constexpr int COLG = 2 * HOUT / 4;        // 4-col groups across [Hn | Hg]
    constexpr int RPG  = 256 / COLG;
    constexpr int RPT  = BR / RPG;            // 16 for H=64, 8 for H=32
    __shared__ float Xs[BR * LDK];

    const int row0 = blockIdx.x * BR;
    const int t = threadIdx.x;

    const int cidx = t % COLG;
    const int ridx = t / COLG;
    const int col4 = cidx * 4;
    const bool nside = (col4 < HOUT);
    const float* W = nside ? Wn : Wg;
    const int wcol = nside ? col4 : (col4 - HOUT);
    const float* xbase = &Xs[(ridx * RPT) * LDK];

    float acc[RPT][4];
#pragma unroll
    for (int i = 0; i < RPT; i++)
        acc[i][0] = acc[i][1] = acc[i][2] = acc[i][3] = 0.f;

    for (int kc = 0; kc < NKCH; kc++) {
        const int k0 = kc * BK;
        if (kc) __syncthreads();

        // Stage X chunk (coalesced float4), BN affine + ReLU on the fly.
        for (int li = t; li < BR * BK / 4; li += 256) {
            int r  = li / (BK / 4);
            int k4 = (li % (BK / 4)) * 4;
            int rr = row0 + r;
            float4 v = make_float4(0.f, 0.f, 0.f, 0.f);
            if (rr < n) v = *(const float4*)&X[(size_t)rr * K + k0 + k4];
            if (AFF) {
                float4 sc = *(const float4*)&scale[k0 + k4];
                float4 sh = *(const float4*)&shift[k0 + k4];
                v.x = fmaxf(v.x * sc.x + sh.x, 0.f);
                v.y = fmaxf(v.y * sc.y + sh.y, 0.f);
                v.z = fmaxf(v.z * sc.z + sh.z, 0.f);
                v.w = fmaxf(v.w * sc.w + sh.w, 0.f);
            }
            *(float4*)&Xs[r * LDK + k4] = v;
        }
        __syncthreads();

#pragma unroll 2
        for (int kk = 0; kk < BK; kk += 4) {
            const float* wp = &W[(k0 + kk) * HOUT + wcol];
            float4 w0 = *(const float4*)&wp[0 * HOUT];
            float4 w1 = *(const float4*)&wp[1 * HOUT];
            float4 w2 = *(const float4*)&wp[2 * HOUT];
            float4 w3 = *(const float4*)&wp[3 * HOUT];
#pragma unroll
            for (int i = 0; i < RPT; i++) {
                float4 xq = *(const float4*)&xbase[i * LDK + kk];  // ds_read_b128, 2-way=free
                acc[i][0] += xq.x * w0.x; acc[i][1] += xq.x * w0.y;
                acc[i][2] += xq.x * w0.z; acc[i][3] += xq.x * w0.w;
                acc[i][0] += xq.y * w1.x; acc[i][1] += xq.y * w1.y;
                acc[i][2] += xq.y * w1.z; acc[i][3] += xq.y * w1.w;
                acc[i][0] += xq.z * w2.x; acc[i][1] += xq.z * w2.y;
                acc[i][2] += xq.z * w2.z; acc[i][3] += xq.z * w2.w;
                acc[i][0] += xq.w * w3.x; acc[i][1] += xq.w * w3.y;
                acc[i][2] += xq.w * w3.z; acc[i][3] += xq.w * w3.w;
            }
        }
    }

    float4 b4 = make_float4(0.f, 0.f, 0.f, 0.f);
    if (nside) {
        if (bnA) { float4 u = *(const float4*)&bnA[wcol]; b4.x += u.x; b4.y += u.y; b4.z += u.z; b4.w += u.w; }
        if (bnB) { float4 u = *(const float4*)&bnB[wcol]; b4.x += u.x; b4.y += u.y; b4.z += u.z; b4.w += u.w; }
    } else if (bgA) {
        float4 u = *(const float4*)&bgA[wcol]; b4.x += u.x; b4.y += u.y; b4.z += u.z; b4.w += u.w;
    }

    float* dst = nside ? Hn : Hg;
#pragma unroll
    for (int i = 0; i < RPT; i++) {
        int rr = row0 + ridx * RPT + i;
        if (rr < n) {
            float4 o;
            o.x = acc[i][0] + b4.x;
            o.y = acc[i][1] + b4.y;
            o.z = acc[i][2] + b4.z;
            o.w = acc[i][3] + b4.w;
            *(float4*)&dst[(size_t)rr * HOUT + wcol] = o;
        }
    }
}

// ---------------------------------------------------------------------------
// SpMM (CSR gather): S[row] += sum_e val[e]*Hg[col[e]]. One (HH/2)-lane group
// per row, float2 per lane. Optionally accumulates BN batch stats with
// striped atomics.
// ---------------------------------------------------------------------------

template <int HH, bool STATS>
__global__ __launch_bounds__(256) void spmm_k(
    const int* __restrict__ rowptr, const int2* __restrict__ cs,
    const float* __restrict__ Hg,
    float* __restrict__ S, float* __restrict__ stats, int n)
{
    constexpr int L  = HH / 2;            // lanes per group (float2 each)
    constexpr int GP = 256 / L;           // groups per block
    const int lane = threadIdx.x % L;
    const int g = threadIdx.x / L;
    const int gid = blockIdx.x * GP + g;
    const int ngroups = gridDim.x * GP;

    float2 sum = make_float2(0.f, 0.f), sq = make_float2(0.f, 0.f);
    for (int row = gid; row < n; row += ngroups) {
        int e0 = rowptr[row], e1 = rowptr[row + 1];
        float2 acc0 = *(const float2*)&S[(size_t)row * HH + lane * 2]; // h_node already here
        float2 acc1 = make_float2(0.f, 0.f);
        int e = e0;
        for (; e + 1 < e1; e += 2) {               // 2-way unroll: break FMA chain
            int2 p0 = cs[e], p1 = cs[e + 1];
            float v0 = __int_as_float(p0.y), v1 = __int_as_float(p1.y);
            float2 h0 = *(const float2*)&Hg[(size_t)p0.x * HH + lane * 2];
            float2 h1 = *(const float2*)&Hg[(size_t)p1.x * HH + lane * 2];
            acc0.x += v0 * h0.x; acc0.y += v0 * h0.y;
            acc1.x += v1 * h1.x; acc1.y += v1 * h1.y;
        }
        if (e < e1) {
            int2 p = cs[e];
            float v = __int_as_float(p.y);
            float2 h = *(const float2*)&Hg[(size_t)p.x * HH + lane * 2];
            acc0.x += v * h.x; acc0.y += v * h.y;
        }
        float2 acc = make_float2(acc0.x + acc1.x, acc0.y + acc1.y);
        *(float2*)&S[(size_t)row * HH + lane * 2] = acc;
        if (STATS) {
            sum.x += acc.x; sum.y += acc.y;
            sq.x += acc.x * acc.x; sq.y += acc.y * acc.y;
        }
    }

    if constexpr (STATS) {
        __shared__ float rs[GP][HH];
        __shared__ float rq[GP][HH];
        rs[g][lane * 2] = sum.x; rs[g][lane * 2 + 1] = sum.y;
        rq[g][lane * 2] = sq.x;  rq[g][lane * 2 + 1] = sq.y;
        __syncthreads();
        if (threadIdx.x < HH) {
            float a = 0.f, b = 0.f;
            for (int w = 0; w < GP; w++) { a += rs[w][threadIdx.x]; b += rq[w][threadIdx.x]; }
            int stripe = blockIdx.x & 7;
            atomicAdd(&stats[stripe * 128 + threadIdx.x], a);
            atomicAdd(&stats[stripe * 128 + HH + threadIdx.x], b);
        }
    }
}

// stats_in: 8 stripes x [sum[64] | sumsq[64]]. Writes BN scale/shift.
__global__ void finalize_k(const float* __restrict__ stats_in,
                           const float* __restrict__ gamma, const float* __restrict__ beta,
                           float* __restrict__ scale, float* __restrict__ shift, float n) {
    int t = threadIdx.x;   // 64
    float sum = 0.f, sq = 0.f;
    for (int s = 0; s < 8; s++) { sum += stats_in[s * 128 + t]; sq += stats_in[s * 128 + 64 + t]; }
    float m = sum / n;
    float var = sq / n - m * m;
    float sc = gamma[t] * rsqrtf(var + BN_EPS);
    scale[t] = sc;
    shift[t] = beta[t] - m * sc;
}

__global__ void gather_k(const float* __restrict__ S, const int* __restrict__ idx,
                         float* __restrict__ out, int total4) {
    int j = blockIdx.x * 256 + threadIdx.x;   // one float4 per thread
    if (j < total4) {
        int r = j / (EMB / 4), c4 = (j % (EMB / 4)) * 4;
        *(float4*)&out[(size_t)j * 4] = *(const float4*)&S[(size_t)idx[r] * EMB + c4];
    }
}

// ---------------------------------------------------------------------------

extern "C" void kernel_launch(void* const* d_in, const int* in_sizes, int n_in,
                              void* d_out, int out_size, void* d_ws, size_t ws_size,
                              hipStream_t stream) {
    const float* features = (const float*)d_in[0];
    const int*   rows     = (const int*)d_in[1];
    const int*   cols     = (const int*)d_in[2];
    const float* vals     = (const float*)d_in[3];
    const int*   idx      = (const int*)d_in[4];
    const float* Wn0 = (const float*)d_in[5];
    const float* bn0 = (const float*)d_in[6];
    const float* Wg0 = (const float*)d_in[7];
    const float* bg0 = (const float*)d_in[8];
    const float* ab0 = (const float*)d_in[9];
    const float* g0  = (const float*)d_in[10];
    const float* b0  = (const float*)d_in[11];
    const float* Wn1 = (const float*)d_in[12];
    const float* Wg1 = (const float*)d_in[13];
    const float* ab1 = (const float*)d_in[14];
    const float* g1  = (const float*)d_in[15];
    const float* b1  = (const float*)d_in[16];
    const float* WnL = (const float*)d_in[17];
    const float* WgL = (const float*)d_in[18];
    const float* abL = (const float*)d_in[19];
    float* out = (float*)d_out;

    // Workspace layout (~85 MB): 3 big activation buffers (reused), CSR, stats.
    float* big0 = (float*)d_ws;                         // Hn0/s0, then HnL/sL
    float* big1 = big0 + (size_t)NNODES * HID;          // Hg0/Hg1, then HgL
    float* big2 = big1 + (size_t)NNODES * HID;          // Hn1/s1
    int*   cnt     = (int*)(big2 + (size_t)NNODES * HID);
    int*   part    = cnt + NNODES;
    int*   rowptr  = part + 1024;
    int*   cursor  = rowptr + NNODES + 1;
    int2*  cs      = (int2*)(cursor + NNODES);          // packed {col, val_bits}
    float* stats   = (float*)(cs + NEDGES);
    float* sums0  = stats;
    float* sums1  = stats + 1024;
    float* scale0 = stats + 2048;
    float* shift0 = stats + 2112;
    float* scale1 = stats + 2176;
    float* shift1 = stats + 2240;

    hipMemsetAsync(cnt, 0, NNODES * sizeof(int), stream);
    hipMemsetAsync(stats, 0, 2048 * sizeof(float), stream);

    const int EB = (NEDGES + 255) / 256;   // 3125
    const int NB = (NNODES + 255) / 256;   // 391
    hist_k<<<EB, 256, 0, stream>>>(rows, cnt, NEDGES);
    scan1_k<<<NB, 256, 0, stream>>>(cnt, part, NNODES);
    scan2_k<<<1, 512, 0, stream>>>(part, NB);
    scan3_k<<<NB, 256, 0, stream>>>(cnt, part, rowptr, cursor, NNODES, NEDGES);
    scatter_k<<<EB, 256, 0, stream>>>(rows, cols, vals, cursor, cs, NEDGES);

    const int GB = (NNODES + 127) / 128;   // 782

    // Layer 0: Hn = X@Wn0 + bn0 + ab0, Hg = X@Wg0 + bg0; s0 = Hn + A@Hg
    gemm2_k<DIN, HID, false><<<GB, 256, 0, stream>>>(
        features, Wn0, Wg0, bn0, ab0, bg0, nullptr, nullptr, big0, big1, NNODES);
    spmm_k<HID, true><<<1600, 256, 0, stream>>>(rowptr, cs, big1, big0, sums0, NNODES);
    finalize_k<<<1, 64, 0, stream>>>(sums0, g0, b0, scale0, shift0, (float)NNODES);

    // Layer 1: x1 = relu(BN(s0)) folded into staging; s1 = Hn1 + A@Hg1 + ab1
    gemm2_k<HID, HID, true><<<GB, 256, 0, stream>>>(
        big0, Wn1, Wg1, ab1, nullptr, nullptr, scale0, shift0, big2, big1, NNODES);
    spmm_k<HID, true><<<1600, 256, 0, stream>>>(rowptr, cs, big1, big2, sums1, NNODES);
    finalize_k<<<1, 64, 0, stream>>>(sums1, g1, b1, scale1, shift1, (float)NNODES);

    // Last: xL = relu(BN(s1)); sL = xL@WnL + A@(xL@WgL) + abL; out = sL[idx]
    gemm2_k<HID, EMB, true><<<GB, 256, 0, stream>>>(
        big2, WnL, WgL, abL, nullptr, nullptr, scale1, shift1, big0, big1, NNODES);
    spmm_k<EMB, false><<<1600, 256, 0, stream>>>(rowptr, cs, big1, big0, nullptr, NNODES);
    gather_k<<<(NIDX * EMB / 4 + 255) / 256, 256, 0, stream>>>(big0, idx, out, NIDX * EMB / 4);
}

// Round 4
// 474.370 us; speedup vs baseline: 1.8679x; 1.8679x over previous
//
#include <hip/hip_runtime.h>

// Problem constants (fixed by the reference).
#define NNODES 100000
#define NEDGES 800000
#define DIN    128
#define HID    64
#define EMB    32
#define NIDX   50000
#define BN_EPS 1e-5f

// ---------------------------------------------------------------------------
// CSR build: histogram -> block scan -> scatter. Rebuilt every call (ws is
// re-poisoned). Edges packed as int2{col, val_bits}.
// ---------------------------------------------------------------------------

__global__ void hist_k(const int* __restrict__ rows, int* __restrict__ cnt, int E) {
    int e = blockIdx.x * 256 + threadIdx.x;
    if (e < E) atomicAdd(&cnt[rows[e]], 1);
}

__global__ void scan1_k(const int* __restrict__ cnt, int* __restrict__ part, int n) {
    __shared__ int s[256];
    int i = blockIdx.x * 256 + threadIdx.x;
    s[threadIdx.x] = (i < n) ? cnt[i] : 0;
    __syncthreads();
    for (int off = 128; off > 0; off >>= 1) {
        if (threadIdx.x < off) s[threadIdx.x] += s[threadIdx.x + off];
        __syncthreads();
    }
    if (threadIdx.x == 0) part[blockIdx.x] = s[0];
}

__global__ void scan2_k(int* part, int nb) {
    __shared__ int s[512];
    int t = threadIdx.x;
    int v = (t < nb) ? part[t] : 0;
    s[t] = v;
    __syncthreads();
    for (int off = 1; off < 512; off <<= 1) {
        int a = (t >= off) ? s[t - off] : 0;
        __syncthreads();
        s[t] += a;
        __syncthreads();
    }
    if (t < nb) part[t] = s[t] - v;   // exclusive prefix of block sums
}

__global__ void scan3_k(const int* __restrict__ cnt, const int* __restrict__ part,
                        int* __restrict__ rowptr, int* __restrict__ cursor, int n, int E) {
    __shared__ int s[256];
    int t = threadIdx.x;
    int i = blockIdx.x * 256 + t;
    int v = (i < n) ? cnt[i] : 0;
    s[t] = v;
    __syncthreads();
    for (int off = 1; off < 256; off <<= 1) {
        int a = (t >= off) ? s[t - off] : 0;
        __syncthreads();
        s[t] += a;
        __syncthreads();
    }
    if (i < n) {
        int ex = part[blockIdx.x] + s[t] - v;   // exclusive
        rowptr[i] = ex;
        cursor[i] = ex;
    }
    if (i == 0) rowptr[n] = E;
}

__global__ void scatter_k(const int* __restrict__ rows, const int* __restrict__ cols,
                          const float* __restrict__ vals, int* __restrict__ cursor,
                          int2* __restrict__ cs, int E) {
    int e = blockIdx.x * 256 + threadIdx.x;
    if (e < E) {
        int r = rows[e];
        int p = atomicAdd(&cursor[r], 1);
        cs[p] = make_int2(cols[e], __float_as_int(vals[e]));
    }
}

// ---------------------------------------------------------------------------
// Fused dual GEMM: Hn = act(X) @ Wn (+biases), Hg = act(X) @ Wg (+bias).
// act = optional per-column BN affine + ReLU applied while staging X in LDS.
//
// BR=128 rows/block, 256 threads, RPT rows x 4 cols per thread.
// K staged in BK=64 chunks: LDS = 128*68*4 = 34.8 KB -> 4 blocks/CU = 4
// waves/SIMD from LDS alone. NO min-waves launch_bounds hint: round 3's
// (256,4) forced a 64-VGPR budget and the allocator spilled the whole
// acc[16][4] to scratch (WRITE_SIZE 50->712 MB, VALUBusy 7%). acc 64 +
// w 16 + temps needs ~110 VGPRs; plain (256) lets it allocate that.
// ---------------------------------------------------------------------------

template <int K, int HOUT, bool AFF>
__global__ __launch_bounds__(256) void gemm2_k(
    const float* __restrict__ X,
    const float* __restrict__ Wn, const float* __restrict__ Wg,   // (K, HOUT) row-major
    const float* __restrict__ bnA, const float* __restrict__ bnB, // optional biases, n-side
    const float* __restrict__ bgA,                                // optional bias, g-side
    const float* __restrict__ scale, const float* __restrict__ shift, // AFF: per-k affine
    float* __restrict__ Hn, float* __restrict__ Hg, int n)
{
    constexpr int BR   = 128;
    constexpr int BK   = (K > 64) ? 64 : K;   // K-chunk staged in LDS
    constexpr int NKCH = K / BK;
    constexpr int LDK  = BK + 4;              // 16B-aligned pad
    constexpr int COLG = 2 * HOUT / 4;        // 4-col groups across [Hn | Hg]
    constexpr int RPG  = 256 / COLG;
    constexpr int RPT  = BR / RPG;            // 16 for H=64, 8 for H=32
    __shared__ float Xs[BR * LDK];

    const int row0 = blockIdx.x * BR;
    const int t = threadIdx.x;

    const int cidx = t % COLG;
    const int ridx = t / COLG;
    const int col4 = cidx * 4;
    const bool nside = (col4 < HOUT);
    const float* W = nside ? Wn : Wg;
    const int wcol = nside ? col4 : (col4 - HOUT);
    const float* xbase = &Xs[(ridx * RPT) * LDK];

    float acc[RPT][4];
#pragma unroll
    for (int i = 0; i < RPT; i++)
        acc[i][0] = acc[i][1] = acc[i][2] = acc[i][3] = 0.f;

    for (int kc = 0; kc < NKCH; kc++) {
        const int k0 = kc * BK;
        if (kc) __syncthreads();

        // Stage X chunk (coalesced float4), BN affine + ReLU on the fly.
        for (int li = t; li < BR * BK / 4; li += 256) {
            int r  = li / (BK / 4);
            int k4 = (li % (BK / 4)) * 4;
            int rr = row0 + r;
            float4 v = make_float4(0.f, 0.f, 0.f, 0.f);
            if (rr < n) v = *(const float4*)&X[(size_t)rr * K + k0 + k4];
            if (AFF) {
                float4 sc = *(const float4*)&scale[k0 + k4];
                float4 sh = *(const float4*)&shift[k0 + k4];
                v.x = fmaxf(v.x * sc.x + sh.x, 0.f);
                v.y = fmaxf(v.y * sc.y + sh.y, 0.f);
                v.z = fmaxf(v.z * sc.z + sh.z, 0.f);
                v.w = fmaxf(v.w * sc.w + sh.w, 0.f);
            }
            *(float4*)&Xs[r * LDK + k4] = v;
        }
        __syncthreads();

#pragma unroll 2
        for (int kk = 0; kk < BK; kk += 4) {
            const float* wp = &W[(k0 + kk) * HOUT + wcol];
            float4 w0 = *(const float4*)&wp[0 * HOUT];
            float4 w1 = *(const float4*)&wp[1 * HOUT];
            float4 w2 = *(const float4*)&wp[2 * HOUT];
            float4 w3 = *(const float4*)&wp[3 * HOUT];
#pragma unroll
            for (int i = 0; i < RPT; i++) {
                float4 xq = *(const float4*)&xbase[i * LDK + kk];  // ds_read_b128, 2-way=free
                acc[i][0] += xq.x * w0.x; acc[i][1] += xq.x * w0.y;
                acc[i][2] += xq.x * w0.z; acc[i][3] += xq.x * w0.w;
                acc[i][0] += xq.y * w1.x; acc[i][1] += xq.y * w1.y;
                acc[i][2] += xq.y * w1.z; acc[i][3] += xq.y * w1.w;
                acc[i][0] += xq.z * w2.x; acc[i][1] += xq.z * w2.y;
                acc[i][2] += xq.z * w2.z; acc[i][3] += xq.z * w2.w;
                acc[i][0] += xq.w * w3.x; acc[i][1] += xq.w * w3.y;
                acc[i][2] += xq.w * w3.z; acc[i][3] += xq.w * w3.w;
            }
        }
    }

    float4 b4 = make_float4(0.f, 0.f, 0.f, 0.f);
    if (nside) {
        if (bnA) { float4 u = *(const float4*)&bnA[wcol]; b4.x += u.x; b4.y += u.y; b4.z += u.z; b4.w += u.w; }
        if (bnB) { float4 u = *(const float4*)&bnB[wcol]; b4.x += u.x; b4.y += u.y; b4.z += u.z; b4.w += u.w; }
    } else if (bgA) {
        float4 u = *(const float4*)&bgA[wcol]; b4.x += u.x; b4.y += u.y; b4.z += u.z; b4.w += u.w;
    }

    float* dst = nside ? Hn : Hg;
#pragma unroll
    for (int i = 0; i < RPT; i++) {
        int rr = row0 + ridx * RPT + i;
        if (rr < n) {
            float4 o;
            o.x = acc[i][0] + b4.x;
            o.y = acc[i][1] + b4.y;
            o.z = acc[i][2] + b4.z;
            o.w = acc[i][3] + b4.w;
            *(float4*)&dst[(size_t)rr * HOUT + wcol] = o;
        }
    }
}

// ---------------------------------------------------------------------------
// SpMM (CSR gather): S[row] += sum_e val[e]*Hg[col[e]]. One (HH/2)-lane group
// per row, float2 per lane. Optionally accumulates BN batch stats with
// striped atomics.
// ---------------------------------------------------------------------------

template <int HH, bool STATS>
__global__ __launch_bounds__(256) void spmm_k(
    const int* __restrict__ rowptr, const int2* __restrict__ cs,
    const float* __restrict__ Hg,
    float* __restrict__ S, float* __restrict__ stats, int n)
{
    constexpr int L  = HH / 2;            // lanes per group (float2 each)
    constexpr int GP = 256 / L;           // groups per block
    const int lane = threadIdx.x % L;
    const int g = threadIdx.x / L;
    const int gid = blockIdx.x * GP + g;
    const int ngroups = gridDim.x * GP;

    float2 sum = make_float2(0.f, 0.f), sq = make_float2(0.f, 0.f);
    for (int row = gid; row < n; row += ngroups) {
        int e0 = rowptr[row], e1 = rowptr[row + 1];
        float2 acc0 = *(const float2*)&S[(size_t)row * HH + lane * 2]; // h_node already here
        float2 acc1 = make_float2(0.f, 0.f);
        int e = e0;
        for (; e + 1 < e1; e += 2) {               // 2-way unroll: break FMA chain
            int2 p0 = cs[e], p1 = cs[e + 1];
            float v0 = __int_as_float(p0.y), v1 = __int_as_float(p1.y);
            float2 h0 = *(const float2*)&Hg[(size_t)p0.x * HH + lane * 2];
            float2 h1 = *(const float2*)&Hg[(size_t)p1.x * HH + lane * 2];
            acc0.x += v0 * h0.x; acc0.y += v0 * h0.y;
            acc1.x += v1 * h1.x; acc1.y += v1 * h1.y;
        }
        if (e < e1) {
            int2 p = cs[e];
            float v = __int_as_float(p.y);
            float2 h = *(const float2*)&Hg[(size_t)p.x * HH + lane * 2];
            acc0.x += v * h.x; acc0.y += v * h.y;
        }
        float2 acc = make_float2(acc0.x + acc1.x, acc0.y + acc1.y);
        *(float2*)&S[(size_t)row * HH + lane * 2] = acc;
        if (STATS) {
            sum.x += acc.x; sum.y += acc.y;
            sq.x += acc.x * acc.x; sq.y += acc.y * acc.y;
        }
    }

    if constexpr (STATS) {
        __shared__ float rs[GP][HH];
        __shared__ float rq[GP][HH];
        rs[g][lane * 2] = sum.x; rs[g][lane * 2 + 1] = sum.y;
        rq[g][lane * 2] = sq.x;  rq[g][lane * 2 + 1] = sq.y;
        __syncthreads();
        if (threadIdx.x < HH) {
            float a = 0.f, b = 0.f;
            for (int w = 0; w < GP; w++) { a += rs[w][threadIdx.x]; b += rq[w][threadIdx.x]; }
            int stripe = blockIdx.x & 7;
            atomicAdd(&stats[stripe * 128 + threadIdx.x], a);
            atomicAdd(&stats[stripe * 128 + HH + threadIdx.x], b);
        }
    }
}

// stats_in: 8 stripes x [sum[64] | sumsq[64]]. Writes BN scale/shift.
__global__ void finalize_k(const float* __restrict__ stats_in,
                           const float* __restrict__ gamma, const float* __restrict__ beta,
                           float* __restrict__ scale, float* __restrict__ shift, float n) {
    int t = threadIdx.x;   // 64
    float sum = 0.f, sq = 0.f;
    for (int s = 0; s < 8; s++) { sum += stats_in[s * 128 + t]; sq += stats_in[s * 128 + 64 + t]; }
    float m = sum / n;
    float var = sq / n - m * m;
    float sc = gamma[t] * rsqrtf(var + BN_EPS);
    scale[t] = sc;
    shift[t] = beta[t] - m * sc;
}

__global__ void gather_k(const float* __restrict__ S, const int* __restrict__ idx,
                         float* __restrict__ out, int total4) {
    int j = blockIdx.x * 256 + threadIdx.x;   // one float4 per thread
    if (j < total4) {
        int r = j / (EMB / 4), c4 = (j % (EMB / 4)) * 4;
        *(float4*)&out[(size_t)j * 4] = *(const float4*)&S[(size_t)idx[r] * EMB + c4];
    }
}

// ---------------------------------------------------------------------------

extern "C" void kernel_launch(void* const* d_in, const int* in_sizes, int n_in,
                              void* d_out, int out_size, void* d_ws, size_t ws_size,
                              hipStream_t stream) {
    const float* features = (const float*)d_in[0];
    const int*   rows     = (const int*)d_in[1];
    const int*   cols     = (const int*)d_in[2];
    const float* vals     = (const float*)d_in[3];
    const int*   idx      = (const int*)d_in[4];
    const float* Wn0 = (const float*)d_in[5];
    const float* bn0 = (const float*)d_in[6];
    const float* Wg0 = (const float*)d_in[7];
    const float* bg0 = (const float*)d_in[8];
    const float* ab0 = (const float*)d_in[9];
    const float* g0  = (const float*)d_in[10];
    const float* b0  = (const float*)d_in[11];
    const float* Wn1 = (const float*)d_in[12];
    const float* Wg1 = (const float*)d_in[13];
    const float* ab1 = (const float*)d_in[14];
    const float* g1  = (const float*)d_in[15];
    const float* b1  = (const float*)d_in[16];
    const float* WnL = (const float*)d_in[17];
    const float* WgL = (const float*)d_in[18];
    const float* abL = (const float*)d_in[19];
    float* out = (float*)d_out;

    // Workspace layout (~85 MB): 3 big activation buffers (reused), CSR, stats.
    float* big0 = (float*)d_ws;                         // Hn0/s0, then HnL/sL
    float* big1 = big0 + (size_t)NNODES * HID;          // Hg0/Hg1, then HgL
    float* big2 = big1 + (size_t)NNODES * HID;          // Hn1/s1
    int*   cnt     = (int*)(big2 + (size_t)NNODES * HID);
    int*   part    = cnt + NNODES;
    int*   rowptr  = part + 1024;
    int*   cursor  = rowptr + NNODES + 1;
    int2*  cs      = (int2*)(cursor + NNODES);          // packed {col, val_bits}
    float* stats   = (float*)(cs + NEDGES);
    float* sums0  = stats;
    float* sums1  = stats + 1024;
    float* scale0 = stats + 2048;
    float* shift0 = stats + 2112;
    float* scale1 = stats + 2176;
    float* shift1 = stats + 2240;

    hipMemsetAsync(cnt, 0, NNODES * sizeof(int), stream);
    hipMemsetAsync(stats, 0, 2048 * sizeof(float), stream);

    const int EB = (NEDGES + 255) / 256;   // 3125
    const int NB = (NNODES + 255) / 256;   // 391
    hist_k<<<EB, 256, 0, stream>>>(rows, cnt, NEDGES);
    scan1_k<<<NB, 256, 0, stream>>>(cnt, part, NNODES);
    scan2_k<<<1, 512, 0, stream>>>(part, NB);
    scan3_k<<<NB, 256, 0, stream>>>(cnt, part, rowptr, cursor, NNODES, NEDGES);
    scatter_k<<<EB, 256, 0, stream>>>(rows, cols, vals, cursor, cs, NEDGES);

    const int GB = (NNODES + 127) / 128;   // 782

    // Layer 0: Hn = X@Wn0 + bn0 + ab0, Hg = X@Wg0 + bg0; s0 = Hn + A@Hg
    gemm2_k<DIN, HID, false><<<GB, 256, 0, stream>>>(
        features, Wn0, Wg0, bn0, ab0, bg0, nullptr, nullptr, big0, big1, NNODES);
    spmm_k<HID, true><<<1600, 256, 0, stream>>>(rowptr, cs, big1, big0, sums0, NNODES);
    finalize_k<<<1, 64, 0, stream>>>(sums0, g0, b0, scale0, shift0, (float)NNODES);

    // Layer 1: x1 = relu(BN(s0)) folded into staging; s1 = Hn1 + A@Hg1 + ab1
    gemm2_k<HID, HID, true><<<GB, 256, 0, stream>>>(
        big0, Wn1, Wg1, ab1, nullptr, nullptr, scale0, shift0, big2, big1, NNODES);
    spmm_k<HID, true><<<1600, 256, 0, stream>>>(rowptr, cs, big1, big2, sums1, NNODES);
    finalize_k<<<1, 64, 0, stream>>>(sums1, g1, b1, scale1, shift1, (float)NNODES);

    // Last: xL = relu(BN(s1)); sL = xL@WnL + A@(xL@WgL) + abL; out = sL[idx]
    gemm2_k<HID, EMB, true><<<GB, 256, 0, stream>>>(
        big2, WnL, WgL, abL, nullptr, nullptr, scale1, shift1, big0, big1, NNODES);
    spmm_k<EMB, false><<<1600, 256, 0, stream>>>(rowptr, cs, big1, big0, nullptr, NNODES);
    gather_k<<<(NIDX * EMB / 4 + 255) / 256, 256, 0, stream>>>(big0, idx, out, NIDX * EMB / 4);
}

// Round 5
// 395.408 us; speedup vs baseline: 2.2409x; 1.1997x over previous
//
#include <hip/hip_runtime.h>

// Problem constants (fixed by the reference).
#define NNODES 100000
#define NEDGES 800000
#define DIN    128
#define HID    64
#define EMB    32
#define NIDX   50000
#define BN_EPS 1e-5f

typedef __attribute__((ext_vector_type(8))) short short8;   // 8 bf16 = 4 VGPR
typedef __attribute__((ext_vector_type(4))) float f32x4;    // MFMA C/D

__device__ inline unsigned short f2bf(float f) {            // RNE, matches HW
    unsigned u = __float_as_uint(f);
    unsigned r = u + 0x7FFFu + ((u >> 16) & 1u);
    return (unsigned short)(r >> 16);
}

// ---------------------------------------------------------------------------
// CSR build: histogram -> block scan -> scatter. Rebuilt every call (ws is
// re-poisoned). Edges packed as int2{col, val_bits}.
// ---------------------------------------------------------------------------

__global__ void hist_k(const int* __restrict__ rows, int* __restrict__ cnt, int E) {
    int e = blockIdx.x * 256 + threadIdx.x;
    if (e < E) atomicAdd(&cnt[rows[e]], 1);
}

__global__ void scan1_k(const int* __restrict__ cnt, int* __restrict__ part, int n) {
    __shared__ int s[256];
    int i = blockIdx.x * 256 + threadIdx.x;
    s[threadIdx.x] = (i < n) ? cnt[i] : 0;
    __syncthreads();
    for (int off = 128; off > 0; off >>= 1) {
        if (threadIdx.x < off) s[threadIdx.x] += s[threadIdx.x + off];
        __syncthreads();
    }
    if (threadIdx.x == 0) part[blockIdx.x] = s[0];
}

__global__ void scan2_k(int* part, int nb) {
    __shared__ int s[512];
    int t = threadIdx.x;
    int v = (t < nb) ? part[t] : 0;
    s[t] = v;
    __syncthreads();
    for (int off = 1; off < 512; off <<= 1) {
        int a = (t >= off) ? s[t - off] : 0;
        __syncthreads();
        s[t] += a;
        __syncthreads();
    }
    if (t < nb) part[t] = s[t] - v;   // exclusive prefix of block sums
}

__global__ void scan3_k(const int* __restrict__ cnt, const int* __restrict__ part,
                        int* __restrict__ rowptr, int* __restrict__ cursor, int n, int E) {
    __shared__ int s[256];
    int t = threadIdx.x;
    int i = blockIdx.x * 256 + t;
    int v = (i < n) ? cnt[i] : 0;
    s[t] = v;
    __syncthreads();
    for (int off = 1; off < 256; off <<= 1) {
        int a = (t >= off) ? s[t - off] : 0;
        __syncthreads();
        s[t] += a;
        __syncthreads();
    }
    if (i < n) {
        int ex = part[blockIdx.x] + s[t] - v;   // exclusive
        rowptr[i] = ex;
        cursor[i] = ex;
    }
    if (i == 0) rowptr[n] = E;
}

__global__ void scatter_k(const int* __restrict__ rows, const int* __restrict__ cols,
                          const float* __restrict__ vals, int* __restrict__ cursor,
                          int2* __restrict__ cs, int E) {
    int e = blockIdx.x * 256 + threadIdx.x;
    if (e < E) {
        int r = rows[e];
        int p = atomicAdd(&cursor[r], 1);
        cs[p] = make_int2(cols[e], __float_as_int(vals[e]));
    }
}

// ---------------------------------------------------------------------------
// W pre-pack: [Wn | Wg] fp32 (K x HOUT each) -> bf16 B-fragment-major:
// Wp[((kb*NT + t)*64 + lane)*8 + j] = W[kb*32 + (lane>>4)*8 + j][t*16 + (lane&15)]
// so the GEMM's B-frag load is one coalesced dwordx4 per lane.
// ---------------------------------------------------------------------------

template <int K, int HOUT>
__global__ void packw_k(const float* __restrict__ Wn, const float* __restrict__ Wg,
                        unsigned short* __restrict__ Wp) {
    constexpr int NC = 2 * HOUT, NT = NC / 16;
    int f = blockIdx.x * 256 + threadIdx.x;
    if (f >= K * NC) return;
    int j = f & 7, lane = (f >> 3) & 63;
    int tt = (f >> 9) % NT, kb = (f >> 9) / NT;
    int k = kb * 32 + ((lane >> 4) * 8) + j;
    int nn = tt * 16 + (lane & 15);
    float v = (nn < HOUT) ? Wn[k * HOUT + nn] : Wg[k * HOUT + (nn - HOUT)];
    Wp[f] = f2bf(v);
}

// ---------------------------------------------------------------------------
// MFMA dual GEMM: [Hn | Hg] = act(X) @ [Wn | Wg] (+ per-col biases).
// act = optional BN affine + ReLU folded into the fp32->bf16 staging.
// Block = 256 thr = 4 waves; wave w owns rows [blk*64 + w*16, +16).
// Per 32-k step: 1 ds_read_b128 (A-frag, layout A[m=lane&15][k=quad*8+j])
// + NT coalesced B-frag dwordx4 from packed W + NT mfma_f32_16x16x32_bf16.
// C/D: col = lane&15, row = quad*4 + reg (verified mapping).
// ---------------------------------------------------------------------------

template <int K, int HOUT, bool AFF>
__global__ __launch_bounds__(256) void gemm2m_k(
    const float* __restrict__ X, const unsigned short* __restrict__ Wp,
    const float* __restrict__ bnA, const float* __restrict__ bnB, // n-side biases
    const float* __restrict__ bgA,                                // g-side bias
    const float* __restrict__ scale, const float* __restrict__ shift,
    float* __restrict__ Hn, float* __restrict__ Hg, int n)
{
    constexpr int NC  = 2 * HOUT, NT = NC / 16, NKB = K / 32;
    constexpr int RS  = K + 8;       // LDS row stride (bf16): +8 keeps b128 16B-aligned
                                     // and spreads rows 4 banks apart (balanced groups)
    __shared__ unsigned short Xs[64 * RS];

    const int row0 = blockIdx.x * 64;
    const int t = threadIdx.x;

    // Stage 64 x K fp32 -> bf16 LDS (affine+relu on the fly).
    for (int li = t; li < 64 * K / 4; li += 256) {
        int r  = li / (K / 4);
        int k4 = (li % (K / 4)) * 4;
        int rr = row0 + r;
        float4 v = make_float4(0.f, 0.f, 0.f, 0.f);
        if (rr < n) v = *(const float4*)&X[(size_t)rr * K + k4];
        if (AFF) {
            float4 sc = *(const float4*)&scale[k4];
            float4 sh = *(const float4*)&shift[k4];
            v.x = fmaxf(v.x * sc.x + sh.x, 0.f);
            v.y = fmaxf(v.y * sc.y + sh.y, 0.f);
            v.z = fmaxf(v.z * sc.z + sh.z, 0.f);
            v.w = fmaxf(v.w * sc.w + sh.w, 0.f);
        }
        unsigned lo = (unsigned)f2bf(v.x) | ((unsigned)f2bf(v.y) << 16);
        unsigned hi = (unsigned)f2bf(v.z) | ((unsigned)f2bf(v.w) << 16);
        *(uint2*)&Xs[r * RS + k4] = make_uint2(lo, hi);
    }
    __syncthreads();

    const int wave = t >> 6, lane = t & 63;
    const int q = lane >> 4, mrow = lane & 15;

    f32x4 acc[NT];
#pragma unroll
    for (int i = 0; i < NT; i++) acc[i] = (f32x4){0.f, 0.f, 0.f, 0.f};

    const short8* wp8 = (const short8*)Wp;
#pragma unroll
    for (int kb = 0; kb < NKB; kb++) {
        short8 a = *(const short8*)&Xs[(wave * 16 + mrow) * RS + kb * 32 + q * 8];
#pragma unroll
        for (int tt = 0; tt < NT; tt++) {
            short8 b = wp8[(kb * NT + tt) * 64 + lane];   // coalesced dwordx4
            acc[tt] = __builtin_amdgcn_mfma_f32_16x16x32_bf16(a, b, acc[tt], 0, 0, 0);
        }
    }

    // Epilogue: bias per output column, scalar stores (4 rows x NT cols/lane).
#pragma unroll
    for (int tt = 0; tt < NT; tt++) {
        int nglob = tt * 16 + mrow;
        bool nside = (nglob < HOUT);
        int c = nside ? nglob : (nglob - HOUT);
        float bias = 0.f;
        if (nside) {
            if (bnA) bias += bnA[c];
            if (bnB) bias += bnB[c];
        } else if (bgA) {
            bias += bgA[c];
        }
        float* dst = nside ? Hn : Hg;
#pragma unroll
        for (int r = 0; r < 4; r++) {
            int rr = row0 + wave * 16 + q * 4 + r;
            if (rr < n) dst[(size_t)rr * HOUT + c] = acc[tt][r] + bias;
        }
    }
}

// ---------------------------------------------------------------------------
// SpMM (CSR gather): S[row] += sum_e val[e]*Hg[col[e]]. One (HH/2)-lane group
// per row, float2 per lane. Optionally accumulates BN batch stats with
// striped atomics. (Unchanged this round.)
// ---------------------------------------------------------------------------

template <int HH, bool STATS>
__global__ __launch_bounds__(256) void spmm_k(
    const int* __restrict__ rowptr, const int2* __restrict__ cs,
    const float* __restrict__ Hg,
    float* __restrict__ S, float* __restrict__ stats, int n)
{
    constexpr int L  = HH / 2;            // lanes per group (float2 each)
    constexpr int GP = 256 / L;           // groups per block
    const int lane = threadIdx.x % L;
    const int g = threadIdx.x / L;
    const int gid = blockIdx.x * GP + g;
    const int ngroups = gridDim.x * GP;

    float2 sum = make_float2(0.f, 0.f), sq = make_float2(0.f, 0.f);
    for (int row = gid; row < n; row += ngroups) {
        int e0 = rowptr[row], e1 = rowptr[row + 1];
        float2 acc0 = *(const float2*)&S[(size_t)row * HH + lane * 2]; // h_node already here
        float2 acc1 = make_float2(0.f, 0.f);
        int e = e0;
        for (; e + 1 < e1; e += 2) {               // 2-way unroll: break FMA chain
            int2 p0 = cs[e], p1 = cs[e + 1];
            float v0 = __int_as_float(p0.y), v1 = __int_as_float(p1.y);
            float2 h0 = *(const float2*)&Hg[(size_t)p0.x * HH + lane * 2];
            float2 h1 = *(const float2*)&Hg[(size_t)p1.x * HH + lane * 2];
            acc0.x += v0 * h0.x; acc0.y += v0 * h0.y;
            acc1.x += v1 * h1.x; acc1.y += v1 * h1.y;
        }
        if (e < e1) {
            int2 p = cs[e];
            float v = __int_as_float(p.y);
            float2 h = *(const float2*)&Hg[(size_t)p.x * HH + lane * 2];
            acc0.x += v * h.x; acc0.y += v * h.y;
        }
        float2 acc = make_float2(acc0.x + acc1.x, acc0.y + acc1.y);
        *(float2*)&S[(size_t)row * HH + lane * 2] = acc;
        if (STATS) {
            sum.x += acc.x; sum.y += acc.y;
            sq.x += acc.x * acc.x; sq.y += acc.y * acc.y;
        }
    }

    if constexpr (STATS) {
        __shared__ float rs[GP][HH];
        __shared__ float rq[GP][HH];
        rs[g][lane * 2] = sum.x; rs[g][lane * 2 + 1] = sum.y;
        rq[g][lane * 2] = sq.x;  rq[g][lane * 2 + 1] = sq.y;
        __syncthreads();
        if (threadIdx.x < HH) {
            float a = 0.f, b = 0.f;
            for (int w = 0; w < GP; w++) { a += rs[w][threadIdx.x]; b += rq[w][threadIdx.x]; }
            int stripe = blockIdx.x & 7;
            atomicAdd(&stats[stripe * 128 + threadIdx.x], a);
            atomicAdd(&stats[stripe * 128 + HH + threadIdx.x], b);
        }
    }
}

// stats_in: 8 stripes x [sum[64] | sumsq[64]]. Writes BN scale/shift.
__global__ void finalize_k(const float* __restrict__ stats_in,
                           const float* __restrict__ gamma, const float* __restrict__ beta,
                           float* __restrict__ scale, float* __restrict__ shift, float n) {
    int t = threadIdx.x;   // 64
    float sum = 0.f, sq = 0.f;
    for (int s = 0; s < 8; s++) { sum += stats_in[s * 128 + t]; sq += stats_in[s * 128 + 64 + t]; }
    float m = sum / n;
    float var = sq / n - m * m;
    float sc = gamma[t] * rsqrtf(var + BN_EPS);
    scale[t] = sc;
    shift[t] = beta[t] - m * sc;
}

__global__ void gather_k(const float* __restrict__ S, const int* __restrict__ idx,
                         float* __restrict__ out, int total4) {
    int j = blockIdx.x * 256 + threadIdx.x;   // one float4 per thread
    if (j < total4) {
        int r = j / (EMB / 4), c4 = (j % (EMB / 4)) * 4;
        *(float4*)&out[(size_t)j * 4] = *(const float4*)&S[(size_t)idx[r] * EMB + c4];
    }
}

// ---------------------------------------------------------------------------

extern "C" void kernel_launch(void* const* d_in, const int* in_sizes, int n_in,
                              void* d_out, int out_size, void* d_ws, size_t ws_size,
                              hipStream_t stream) {
    const float* features = (const float*)d_in[0];
    const int*   rows     = (const int*)d_in[1];
    const int*   cols     = (const int*)d_in[2];
    const float* vals     = (const float*)d_in[3];
    const int*   idx      = (const int*)d_in[4];
    const float* Wn0 = (const float*)d_in[5];
    const float* bn0 = (const float*)d_in[6];
    const float* Wg0 = (const float*)d_in[7];
    const float* bg0 = (const float*)d_in[8];
    const float* ab0 = (const float*)d_in[9];
    const float* g0  = (const float*)d_in[10];
    const float* b0  = (const float*)d_in[11];
    const float* Wn1 = (const float*)d_in[12];
    const float* Wg1 = (const float*)d_in[13];
    const float* ab1 = (const float*)d_in[14];
    const float* g1  = (const float*)d_in[15];
    const float* b1  = (const float*)d_in[16];
    const float* WnL = (const float*)d_in[17];
    const float* WgL = (const float*)d_in[18];
    const float* abL = (const float*)d_in[19];
    float* out = (float*)d_out;

    // Workspace layout (~84.7 MB), all sub-buffers 16B-aligned.
    float* big0 = (float*)d_ws;                         // Hn0/s0, then HnL/sL
    float* big1 = big0 + (size_t)NNODES * HID;          // Hg0/Hg1, then HgL
    float* big2 = big1 + (size_t)NNODES * HID;          // Hn1/s1
    int*   cnt     = (int*)(big2 + (size_t)NNODES * HID);
    int*   part    = cnt + NNODES;
    int*   rowptr  = part + 1024;
    int*   cursor  = rowptr + (NNODES + 4);             // +4 pad keeps 16B alignment
    int2*  cs      = (int2*)(cursor + NNODES);          // packed {col, val_bits}
    float* stats   = (float*)(cs + NEDGES);
    float* sums0  = stats;
    float* sums1  = stats + 1024;
    float* scale0 = stats + 2048;
    float* shift0 = stats + 2112;
    float* scale1 = stats + 2176;
    float* shift1 = stats + 2240;
    unsigned short* Wp0 = (unsigned short*)(stats + 2304);     // 128x128 bf16
    unsigned short* Wp1 = Wp0 + DIN * 2 * HID;                 // 64x128 bf16
    unsigned short* WpL = Wp1 + HID * 2 * HID;                 // 64x64  bf16

    hipMemsetAsync(cnt, 0, NNODES * sizeof(int), stream);
    hipMemsetAsync(stats, 0, 2048 * sizeof(float), stream);

    const int EB = (NEDGES + 255) / 256;   // 3125
    const int NB = (NNODES + 255) / 256;   // 391
    hist_k<<<EB, 256, 0, stream>>>(rows, cnt, NEDGES);
    scan1_k<<<NB, 256, 0, stream>>>(cnt, part, NNODES);
    scan2_k<<<1, 512, 0, stream>>>(part, NB);
    scan3_k<<<NB, 256, 0, stream>>>(cnt, part, rowptr, cursor, NNODES, NEDGES);
    scatter_k<<<EB, 256, 0, stream>>>(rows, cols, vals, cursor, cs, NEDGES);

    packw_k<DIN, HID><<<(DIN * 2 * HID + 255) / 256, 256, 0, stream>>>(Wn0, Wg0, Wp0);
    packw_k<HID, HID><<<(HID * 2 * HID + 255) / 256, 256, 0, stream>>>(Wn1, Wg1, Wp1);
    packw_k<HID, EMB><<<(HID * 2 * EMB + 255) / 256, 256, 0, stream>>>(WnL, WgL, WpL);

    const int GBm = (NNODES + 63) / 64;    // 1563

    // Layer 0: Hn = X@Wn0 + bn0 + ab0, Hg = X@Wg0 + bg0; s0 = Hn + A@Hg
    gemm2m_k<DIN, HID, false><<<GBm, 256, 0, stream>>>(
        features, Wp0, bn0, ab0, bg0, nullptr, nullptr, big0, big1, NNODES);
    spmm_k<HID, true><<<1600, 256, 0, stream>>>(rowptr, cs, big1, big0, sums0, NNODES);
    finalize_k<<<1, 64, 0, stream>>>(sums0, g0, b0, scale0, shift0, (float)NNODES);

    // Layer 1: x1 = relu(BN(s0)) folded into staging; s1 = Hn1 + A@Hg1 + ab1
    gemm2m_k<HID, HID, true><<<GBm, 256, 0, stream>>>(
        big0, Wp1, ab1, nullptr, nullptr, scale0, shift0, big2, big1, NNODES);
    spmm_k<HID, true><<<1600, 256, 0, stream>>>(rowptr, cs, big1, big2, sums1, NNODES);
    finalize_k<<<1, 64, 0, stream>>>(sums1, g1, b1, scale1, shift1, (float)NNODES);

    // Last: xL = relu(BN(s1)); sL = xL@WnL + A@(xL@WgL) + abL; out = sL[idx]
    gemm2m_k<HID, EMB, true><<<GBm, 256, 0, stream>>>(
        big2, WpL, abL, nullptr, nullptr, scale1, shift1, big0, big1, NNODES);
    spmm_k<EMB, false><<<1600, 256, 0, stream>>>(rowptr, cs, big1, big0, nullptr, NNODES);
    gather_k<<<(NIDX * EMB / 4 + 255) / 256, 256, 0, stream>>>(big0, idx, out, NIDX * EMB / 4);
}

// Round 6
// 333.436 us; speedup vs baseline: 2.6574x; 1.1859x over previous
//
#include <hip/hip_runtime.h>

// Problem constants (fixed by the reference).
#define NNODES 100000
#define NEDGES 800000
#define DIN    128
#define HID    64
#define EMB    32
#define NIDX   50000
#define BN_EPS 1e-5f

typedef __attribute__((ext_vector_type(8))) short short8;   // 8 bf16 = 4 VGPR
typedef __attribute__((ext_vector_type(4))) float f32x4;    // MFMA C/D

__device__ inline unsigned short f2bf(float f) {            // RNE, matches HW
    unsigned u = __float_as_uint(f);
    unsigned r = u + 0x7FFFu + ((u >> 16) & 1u);
    return (unsigned short)(r >> 16);
}

// ---------------------------------------------------------------------------
// CSR build, round-6 scheme (atomic-return sharded per XCD, scatter atomic-free):
//   histrank: rank[e] = atomicAdd(&cntS[blk&7][rows[e]], 1)   (XCD-local lines)
//   sumshard: cnt[r] = sum_s cntS[s][r]; base[r*8+s] = exclusive prefix
//   scan1/2/3: cnt -> rowptr (block scan)
//   scatter:  cs[rowptr[r] + base[r*8+s] + rank[e]] = {col, val}  (no atomics)
// ---------------------------------------------------------------------------

__global__ void histrank_k(const int* __restrict__ rows, int* __restrict__ cntS,
                           int* __restrict__ rank, int E) {
    int e = blockIdx.x * 256 + threadIdx.x;
    if (e < E) {
        int s = blockIdx.x & 7;
        rank[e] = atomicAdd(&cntS[s * NNODES + rows[e]], 1);
    }
}

__global__ void sumshard_k(const int* __restrict__ cntS, int* __restrict__ base,
                           int* __restrict__ cnt, int n) {
    int r = blockIdx.x * 256 + threadIdx.x;
    if (r >= n) return;
    int c = 0;
    int b[8];
#pragma unroll
    for (int s = 0; s < 8; s++) { b[s] = c; c += cntS[s * NNODES + r]; }
    cnt[r] = c;
    *(int4*)&base[r * 8]     = make_int4(b[0], b[1], b[2], b[3]);
    *(int4*)&base[r * 8 + 4] = make_int4(b[4], b[5], b[6], b[7]);
}

__global__ void scan1_k(const int* __restrict__ cnt, int* __restrict__ part, int n) {
    __shared__ int s[256];
    int i = blockIdx.x * 256 + threadIdx.x;
    s[threadIdx.x] = (i < n) ? cnt[i] : 0;
    __syncthreads();
    for (int off = 128; off > 0; off >>= 1) {
        if (threadIdx.x < off) s[threadIdx.x] += s[threadIdx.x + off];
        __syncthreads();
    }
    if (threadIdx.x == 0) part[blockIdx.x] = s[0];
}

__global__ void scan2_k(int* part, int nb) {
    __shared__ int s[512];
    int t = threadIdx.x;
    int v = (t < nb) ? part[t] : 0;
    s[t] = v;
    __syncthreads();
    for (int off = 1; off < 512; off <<= 1) {
        int a = (t >= off) ? s[t - off] : 0;
        __syncthreads();
        s[t] += a;
        __syncthreads();
    }
    if (t < nb) part[t] = s[t] - v;   // exclusive prefix of block sums
}

__global__ void scan3_k(const int* __restrict__ cnt, const int* __restrict__ part,
                        int* __restrict__ rowptr, int n, int E) {
    __shared__ int s[256];
    int t = threadIdx.x;
    int i = blockIdx.x * 256 + t;
    int v = (i < n) ? cnt[i] : 0;
    s[t] = v;
    __syncthreads();
    for (int off = 1; off < 256; off <<= 1) {
        int a = (t >= off) ? s[t - off] : 0;
        __syncthreads();
        s[t] += a;
        __syncthreads();
    }
    if (i < n) rowptr[i] = part[blockIdx.x] + s[t] - v;   // exclusive
    if (i == 0) rowptr[n] = E;
}

__global__ void scatter_k(const int* __restrict__ rows, const int* __restrict__ cols,
                          const float* __restrict__ vals, const int* __restrict__ rank,
                          const int* __restrict__ base, const int* __restrict__ rowptr,
                          int2* __restrict__ cs, int E) {
    int e = blockIdx.x * 256 + threadIdx.x;
    if (e < E) {
        int r = rows[e];
        int s = blockIdx.x & 7;                 // must match histrank's shard choice
        int pos = rowptr[r] + base[r * 8 + s] + rank[e];
        cs[pos] = make_int2(cols[e], __float_as_int(vals[e]));
    }
}

// ---------------------------------------------------------------------------
// W pre-pack: [Wn | Wg] fp32 (K x HOUT each) -> bf16 B-fragment-major.
// ---------------------------------------------------------------------------

template <int K, int HOUT>
__global__ void packw_k(const float* __restrict__ Wn, const float* __restrict__ Wg,
                        unsigned short* __restrict__ Wp) {
    constexpr int NC = 2 * HOUT, NT = NC / 16;
    int f = blockIdx.x * 256 + threadIdx.x;
    if (f >= K * NC) return;
    int j = f & 7, lane = (f >> 3) & 63;
    int tt = (f >> 9) % NT, kb = (f >> 9) / NT;
    int k = kb * 32 + ((lane >> 4) * 8) + j;
    int nn = tt * 16 + (lane & 15);
    float v = (nn < HOUT) ? Wn[k * HOUT + nn] : Wg[k * HOUT + (nn - HOUT)];
    Wp[f] = f2bf(v);
}

// ---------------------------------------------------------------------------
// MFMA dual GEMM: Hn (fp32) and Hg (bf16) = act(X) @ [Wn | Wg] (+ biases).
// Hg is stored bf16: halves SpMM gather traffic; rounding is within budget.
// ---------------------------------------------------------------------------

template <int K, int HOUT, bool AFF>
__global__ __launch_bounds__(256) void gemm2m_k(
    const float* __restrict__ X, const unsigned short* __restrict__ Wp,
    const float* __restrict__ bnA, const float* __restrict__ bnB, // n-side biases
    const float* __restrict__ bgA,                                // g-side bias
    const float* __restrict__ scale, const float* __restrict__ shift,
    float* __restrict__ Hn, unsigned short* __restrict__ Hgb, int n)
{
    constexpr int NC  = 2 * HOUT, NT = NC / 16, NKB = K / 32;
    constexpr int RS  = K + 8;
    __shared__ unsigned short Xs[64 * RS];

    const int row0 = blockIdx.x * 64;
    const int t = threadIdx.x;

    // Stage 64 x K fp32 -> bf16 LDS (affine+relu on the fly).
    for (int li = t; li < 64 * K / 4; li += 256) {
        int r  = li / (K / 4);
        int k4 = (li % (K / 4)) * 4;
        int rr = row0 + r;
        float4 v = make_float4(0.f, 0.f, 0.f, 0.f);
        if (rr < n) v = *(const float4*)&X[(size_t)rr * K + k4];
        if (AFF) {
            float4 sc = *(const float4*)&scale[k4];
            float4 sh = *(const float4*)&shift[k4];
            v.x = fmaxf(v.x * sc.x + sh.x, 0.f);
            v.y = fmaxf(v.y * sc.y + sh.y, 0.f);
            v.z = fmaxf(v.z * sc.z + sh.z, 0.f);
            v.w = fmaxf(v.w * sc.w + sh.w, 0.f);
        }
        unsigned lo = (unsigned)f2bf(v.x) | ((unsigned)f2bf(v.y) << 16);
        unsigned hi = (unsigned)f2bf(v.z) | ((unsigned)f2bf(v.w) << 16);
        *(uint2*)&Xs[r * RS + k4] = make_uint2(lo, hi);
    }
    __syncthreads();

    const int wave = t >> 6, lane = t & 63;
    const int q = lane >> 4, mrow = lane & 15;

    f32x4 acc[NT];
#pragma unroll
    for (int i = 0; i < NT; i++) acc[i] = (f32x4){0.f, 0.f, 0.f, 0.f};

    const short8* wp8 = (const short8*)Wp;
#pragma unroll
    for (int kb = 0; kb < NKB; kb++) {
        short8 a = *(const short8*)&Xs[(wave * 16 + mrow) * RS + kb * 32 + q * 8];
#pragma unroll
        for (int tt = 0; tt < NT; tt++) {
            short8 b = wp8[(kb * NT + tt) * 64 + lane];   // coalesced dwordx4
            acc[tt] = __builtin_amdgcn_mfma_f32_16x16x32_bf16(a, b, acc[tt], 0, 0, 0);
        }
    }

    // Epilogue. C/D: col = lane&15 (within 16-col tile tt), row = q*4 + reg.
#pragma unroll
    for (int tt = 0; tt < NT; tt++) {
        int nglob = tt * 16 + mrow;
        bool nside = (nglob < HOUT);
        int c = nside ? nglob : (nglob - HOUT);
        float bias = 0.f;
        if (nside) {
            if (bnA) bias += bnA[c];
            if (bnB) bias += bnB[c];
        } else if (bgA) {
            bias += bgA[c];
        }
#pragma unroll
        for (int r = 0; r < 4; r++) {
            int rr = row0 + wave * 16 + q * 4 + r;
            if (rr < n) {
                float o = acc[tt][r] + bias;
                if (nside) Hn[(size_t)rr * HOUT + c] = o;
                else       Hgb[(size_t)rr * HOUT + c] = f2bf(o);
            }
        }
    }
}

// ---------------------------------------------------------------------------
// SpMM (CSR gather): S[row] += sum_e val[e]*Hg[col[e]], Hg in bf16.
// One (HH/4)-lane group per row, 4 bf16 (uint2) per lane per edge.
// Optionally accumulates BN batch stats with striped atomics.
// ---------------------------------------------------------------------------

template <int HH, bool STATS>
__global__ __launch_bounds__(256) void spmm_k(
    const int* __restrict__ rowptr, const int2* __restrict__ cs,
    const unsigned short* __restrict__ Hgb,
    float* __restrict__ S, float* __restrict__ stats, int n)
{
    constexpr int L  = HH / 4;            // lanes per group (4 values each)
    constexpr int GP = 256 / L;           // groups per block
    const int lane = threadIdx.x % L;
    const int g = threadIdx.x / L;
    const int gid = blockIdx.x * GP + g;
    const int ngroups = gridDim.x * GP;
    const int c0 = lane * 4;

    float4 sum = make_float4(0.f, 0.f, 0.f, 0.f);
    float4 sq  = make_float4(0.f, 0.f, 0.f, 0.f);
    for (int row = gid; row < n; row += ngroups) {
        int e0 = rowptr[row], e1 = rowptr[row + 1];
        float4 a0 = *(const float4*)&S[(size_t)row * HH + c0];  // h_node (+bias)
        float4 a1 = make_float4(0.f, 0.f, 0.f, 0.f);
        int e = e0;
        for (; e + 1 < e1; e += 2) {               // 2-way unroll
            int2 p0 = cs[e], p1 = cs[e + 1];
            float v0 = __int_as_float(p0.y), v1 = __int_as_float(p1.y);
            uint2 h0 = *(const uint2*)&Hgb[(size_t)p0.x * HH + c0];
            uint2 h1 = *(const uint2*)&Hgb[(size_t)p1.x * HH + c0];
            a0.x += v0 * __uint_as_float(h0.x << 16);
            a0.y += v0 * __uint_as_float(h0.x & 0xffff0000u);
            a0.z += v0 * __uint_as_float(h0.y << 16);
            a0.w += v0 * __uint_as_float(h0.y & 0xffff0000u);
            a1.x += v1 * __uint_as_float(h1.x << 16);
            a1.y += v1 * __uint_as_float(h1.x & 0xffff0000u);
            a1.z += v1 * __uint_as_float(h1.y << 16);
            a1.w += v1 * __uint_as_float(h1.y & 0xffff0000u);
        }
        if (e < e1) {
            int2 p = cs[e];
            float v = __int_as_float(p.y);
            uint2 h = *(const uint2*)&Hgb[(size_t)p.x * HH + c0];
            a0.x += v * __uint_as_float(h.x << 16);
            a0.y += v * __uint_as_float(h.x & 0xffff0000u);
            a0.z += v * __uint_as_float(h.y << 16);
            a0.w += v * __uint_as_float(h.y & 0xffff0000u);
        }
        float4 acc = make_float4(a0.x + a1.x, a0.y + a1.y, a0.z + a1.z, a0.w + a1.w);
        *(float4*)&S[(size_t)row * HH + c0] = acc;
        if (STATS) {
            sum.x += acc.x; sum.y += acc.y; sum.z += acc.z; sum.w += acc.w;
            sq.x += acc.x * acc.x; sq.y += acc.y * acc.y;
            sq.z += acc.z * acc.z; sq.w += acc.w * acc.w;
        }
    }

    if constexpr (STATS) {
        __shared__ float rs[GP][HH];
        __shared__ float rq[GP][HH];
        *(float4*)&rs[g][c0] = sum;
        *(float4*)&rq[g][c0] = sq;
        __syncthreads();
        if (threadIdx.x < HH) {
            float a = 0.f, b = 0.f;
            for (int w = 0; w < GP; w++) { a += rs[w][threadIdx.x]; b += rq[w][threadIdx.x]; }
            int stripe = blockIdx.x & 7;
            atomicAdd(&stats[stripe * 128 + threadIdx.x], a);
            atomicAdd(&stats[stripe * 128 + HH + threadIdx.x], b);
        }
    }
}

// stats_in: 8 stripes x [sum[64] | sumsq[64]]. Writes BN scale/shift.
__global__ void finalize_k(const float* __restrict__ stats_in,
                           const float* __restrict__ gamma, const float* __restrict__ beta,
                           float* __restrict__ scale, float* __restrict__ shift, float n) {
    int t = threadIdx.x;   // 64
    float sum = 0.f, sq = 0.f;
    for (int s = 0; s < 8; s++) { sum += stats_in[s * 128 + t]; sq += stats_in[s * 128 + 64 + t]; }
    float m = sum / n;
    float var = sq / n - m * m;
    float sc = gamma[t] * rsqrtf(var + BN_EPS);
    scale[t] = sc;
    shift[t] = beta[t] - m * sc;
}

__global__ void gather_k(const float* __restrict__ S, const int* __restrict__ idx,
                         float* __restrict__ out, int total4) {
    int j = blockIdx.x * 256 + threadIdx.x;   // one float4 per thread
    if (j < total4) {
        int r = j / (EMB / 4), c4 = (j % (EMB / 4)) * 4;
        *(float4*)&out[(size_t)j * 4] = *(const float4*)&S[(size_t)idx[r] * EMB + c4];
    }
}

// ---------------------------------------------------------------------------

extern "C" void kernel_launch(void* const* d_in, const int* in_sizes, int n_in,
                              void* d_out, int out_size, void* d_ws, size_t ws_size,
                              hipStream_t stream) {
    const float* features = (const float*)d_in[0];
    const int*   rows     = (const int*)d_in[1];
    const int*   cols     = (const int*)d_in[2];
    const float* vals     = (const float*)d_in[3];
    const int*   idx      = (const int*)d_in[4];
    const float* Wn0 = (const float*)d_in[5];
    const float* bn0 = (const float*)d_in[6];
    const float* Wg0 = (const float*)d_in[7];
    const float* bg0 = (const float*)d_in[8];
    const float* ab0 = (const float*)d_in[9];
    const float* g0  = (const float*)d_in[10];
    const float* b0  = (const float*)d_in[11];
    const float* Wn1 = (const float*)d_in[12];
    const float* Wg1 = (const float*)d_in[13];
    const float* ab1 = (const float*)d_in[14];
    const float* g1  = (const float*)d_in[15];
    const float* b1  = (const float*)d_in[16];
    const float* WnL = (const float*)d_in[17];
    const float* WgL = (const float*)d_in[18];
    const float* abL = (const float*)d_in[19];
    float* out = (float*)d_out;

    // Workspace layout (~81 MB), all sub-buffers 16B-aligned.
    float* big0 = (float*)d_ws;                         // Hn0/s0, then HnL/sL
    float* big2 = big0 + (size_t)NNODES * HID;          // Hn1/s1
    unsigned short* Hgb = (unsigned short*)(big2 + (size_t)NNODES * HID); // bf16 Hg (all layers)
    int*   cnt     = (int*)(Hgb + (size_t)NNODES * HID);
    int*   part    = cnt + NNODES;
    int*   rowptr  = part + 1024;
    int*   rank    = rowptr + (NNODES + 4);
    int*   cntS    = rank + NEDGES;                     // 8 x NNODES
    int*   base    = cntS + 8 * NNODES;                 // NNODES x 8
    int2*  cs      = (int2*)(base + 8 * NNODES);        // packed {col, val_bits}
    float* stats   = (float*)(cs + NEDGES);
    float* sums0  = stats;
    float* sums1  = stats + 1024;
    float* scale0 = stats + 2048;
    float* shift0 = stats + 2112;
    float* scale1 = stats + 2176;
    float* shift1 = stats + 2240;
    unsigned short* Wp0 = (unsigned short*)(stats + 2304);     // 128x128 bf16
    unsigned short* Wp1 = Wp0 + DIN * 2 * HID;                 // 64x128 bf16
    unsigned short* WpL = Wp1 + HID * 2 * HID;                 // 64x64  bf16

    hipMemsetAsync(cntS, 0, 8 * NNODES * sizeof(int), stream);
    hipMemsetAsync(stats, 0, 2048 * sizeof(float), stream);

    const int EB = (NEDGES + 255) / 256;   // 3125
    const int NB = (NNODES + 255) / 256;   // 391
    histrank_k<<<EB, 256, 0, stream>>>(rows, cntS, rank, NEDGES);
    sumshard_k<<<NB, 256, 0, stream>>>(cntS, base, cnt, NNODES);
    scan1_k<<<NB, 256, 0, stream>>>(cnt, part, NNODES);
    scan2_k<<<1, 512, 0, stream>>>(part, NB);
    scan3_k<<<NB, 256, 0, stream>>>(cnt, part, rowptr, NNODES, NEDGES);
    scatter_k<<<EB, 256, 0, stream>>>(rows, cols, vals, rank, base, rowptr, cs, NEDGES);

    packw_k<DIN, HID><<<(DIN * 2 * HID + 255) / 256, 256, 0, stream>>>(Wn0, Wg0, Wp0);
    packw_k<HID, HID><<<(HID * 2 * HID + 255) / 256, 256, 0, stream>>>(Wn1, Wg1, Wp1);
    packw_k<HID, EMB><<<(HID * 2 * EMB + 255) / 256, 256, 0, stream>>>(WnL, WgL, WpL);

    const int GBm = (NNODES + 63) / 64;    // 1563

    // Layer 0: Hn = X@Wn0 + bn0 + ab0, Hg = X@Wg0 + bg0; s0 = Hn + A@Hg
    gemm2m_k<DIN, HID, false><<<GBm, 256, 0, stream>>>(
        features, Wp0, bn0, ab0, bg0, nullptr, nullptr, big0, Hgb, NNODES);
    spmm_k<HID, true><<<1600, 256, 0, stream>>>(rowptr, cs, Hgb, big0, sums0, NNODES);
    finalize_k<<<1, 64, 0, stream>>>(sums0, g0, b0, scale0, shift0, (float)NNODES);

    // Layer 1: x1 = relu(BN(s0)) folded into staging; s1 = Hn1 + A@Hg1 + ab1
    gemm2m_k<HID, HID, true><<<GBm, 256, 0, stream>>>(
        big0, Wp1, ab1, nullptr, nullptr, scale0, shift0, big2, Hgb, NNODES);
    spmm_k<HID, true><<<1600, 256, 0, stream>>>(rowptr, cs, Hgb, big2, sums1, NNODES);
    finalize_k<<<1, 64, 0, stream>>>(sums1, g1, b1, scale1, shift1, (float)NNODES);

    // Last: xL = relu(BN(s1)); sL = xL@WnL + A@(xL@WgL) + abL; out = sL[idx]
    gemm2m_k<HID, EMB, true><<<GBm, 256, 0, stream>>>(
        big2, WpL, abL, nullptr, nullptr, scale1, shift1, big0, Hgb, NNODES);
    spmm_k<EMB, false><<<1600, 256, 0, stream>>>(rowptr, cs, Hgb, big0, nullptr, NNODES);
    gather_k<<<(NIDX * EMB / 4 + 255) / 256, 256, 0, stream>>>(big0, idx, out, NIDX * EMB / 4);
}

// Round 7
// 314.371 us; speedup vs baseline: 2.8185x; 1.0606x over previous
//
#include <hip/hip_runtime.h>

// Problem constants (fixed by the reference).
#define NNODES 100000
#define NEDGES 800000
#define DIN    128
#define HID    64
#define EMB    32
#define NIDX   50000
#define BN_EPS 1e-5f

typedef __attribute__((ext_vector_type(8))) short short8;   // 8 bf16 = 4 VGPR
typedef __attribute__((ext_vector_type(4))) float f32x4;    // MFMA C/D

__device__ inline unsigned short f2bf(float f) {            // RNE, matches HW
    unsigned u = __float_as_uint(f);
    unsigned r = u + 0x7FFFu + ((u >> 16) & 1u);
    return (unsigned short)(r >> 16);
}
__device__ inline float bf2f_lo(unsigned u) { return __uint_as_float(u << 16); }
__device__ inline float bf2f_hi(unsigned u) { return __uint_as_float(u & 0xffff0000u); }

// ---------------------------------------------------------------------------
// W pre-pack (all three layers in ONE kernel): fp32 [Wn|Wg] -> bf16
// B-fragment-major so GEMM B-loads are coalesced dwordx4.
// ---------------------------------------------------------------------------

__device__ inline void pack_seg(const float* __restrict__ Wn, const float* __restrict__ Wg,
                                unsigned short* __restrict__ Wp, int HOUT, int l2nt, int f) {
    int j = f & 7, lane = (f >> 3) & 63, g = f >> 9;
    int tt = g & ((1 << l2nt) - 1), kb = g >> l2nt;
    int k = kb * 32 + ((lane >> 4) * 8) + j;
    int nn = tt * 16 + (lane & 15);
    float v = (nn < HOUT) ? Wn[k * HOUT + nn] : Wg[k * HOUT + (nn - HOUT)];
    Wp[f] = f2bf(v);
}

__global__ void packall_k(const float* Wn0, const float* Wg0, const float* Wn1,
                          const float* Wg1, const float* WnL, const float* WgL,
                          unsigned short* Wp0, unsigned short* Wp1, unsigned short* WpL) {
    int f = blockIdx.x * 256 + threadIdx.x;
    if (f < 16384)      pack_seg(Wn0, Wg0, Wp0, 64, 3, f);           // 128x128
    else if (f < 24576) pack_seg(Wn1, Wg1, Wp1, 64, 3, f - 16384);   // 64x128
    else if (f < 28672) pack_seg(WnL, WgL, WpL, 32, 2, f - 24576);   // 64x64
}

// ---------------------------------------------------------------------------
// MFMA dual-GEMM body (shared by fused0_k and gemm_k).
// [Hn | Hg] = act(X) @ [Wn | Wg] (+ per-col biases); Hg always bf16 out;
// Hn bf16 (HNBF) or fp32. X fp32 (layer 0) or bf16 (later layers).
// AFF: BN scale/shift recomputed in-block from striped sums (folds finalize).
// ---------------------------------------------------------------------------

template <int K, int HOUT, bool AFF, bool XBF, bool HNBF>
__device__ void gemm_body(const void* __restrict__ Xv, const unsigned short* __restrict__ Wp,
                          const float* __restrict__ bnA, const float* __restrict__ bnB,
                          const float* __restrict__ bgA,
                          const float* __restrict__ sums, const float* __restrict__ gamma,
                          const float* __restrict__ beta,
                          float* __restrict__ Hnf, unsigned short* __restrict__ Hnb,
                          unsigned short* __restrict__ Hgb, int n, int blk)
{
    constexpr int NT = 2 * HOUT / 16, NKB = K / 32;
    constexpr int RS = K + 8;
    __shared__ unsigned short Xs[64 * RS];
    __shared__ float sSc[64], sSh[64];

    const int row0 = blk * 64;
    const int t = threadIdx.x;

    if (AFF) {               // in-block BN finalize: 1KB of reads, once per block
        if (t < 64) {
            float sum = 0.f, sq = 0.f;
#pragma unroll
            for (int s = 0; s < 8; s++) { sum += sums[s * 128 + t]; sq += sums[s * 128 + 64 + t]; }
            float m = sum / (float)NNODES;
            float var = sq / (float)NNODES - m * m;
            float sc = gamma[t] * rsqrtf(var + BN_EPS);
            sSc[t] = sc; sSh[t] = beta[t] - m * sc;
        }
        __syncthreads();
    }

    // Stage 64 x K -> bf16 LDS, 8 k-cols per step (affine+relu on the fly).
    for (int li = t; li < 64 * K / 8; li += 256) {
        int r  = li / (K / 8);
        int k8 = (li % (K / 8)) * 8;
        int rr = row0 + r;
        float v[8];
        if (XBF) {
            uint4 u = (rr < n) ? *(const uint4*)((const unsigned short*)Xv + (size_t)rr * K + k8)
                               : make_uint4(0, 0, 0, 0);
            v[0] = bf2f_lo(u.x); v[1] = bf2f_hi(u.x);
            v[2] = bf2f_lo(u.y); v[3] = bf2f_hi(u.y);
            v[4] = bf2f_lo(u.z); v[5] = bf2f_hi(u.z);
            v[6] = bf2f_lo(u.w); v[7] = bf2f_hi(u.w);
        } else {
            const float* Xf = (const float*)Xv;
            float4 a = make_float4(0.f, 0.f, 0.f, 0.f), b = a;
            if (rr < n) {
                a = *(const float4*)&Xf[(size_t)rr * K + k8];
                b = *(const float4*)&Xf[(size_t)rr * K + k8 + 4];
            }
            v[0] = a.x; v[1] = a.y; v[2] = a.z; v[3] = a.w;
            v[4] = b.x; v[5] = b.y; v[6] = b.z; v[7] = b.w;
        }
        if (AFF) {
#pragma unroll
            for (int i = 0; i < 8; i++) v[i] = fmaxf(v[i] * sSc[k8 + i] + sSh[k8 + i], 0.f);
        }
        uint4 o;
        o.x = (unsigned)f2bf(v[0]) | ((unsigned)f2bf(v[1]) << 16);
        o.y = (unsigned)f2bf(v[2]) | ((unsigned)f2bf(v[3]) << 16);
        o.z = (unsigned)f2bf(v[4]) | ((unsigned)f2bf(v[5]) << 16);
        o.w = (unsigned)f2bf(v[6]) | ((unsigned)f2bf(v[7]) << 16);
        *(uint4*)&Xs[r * RS + k8] = o;
    }
    __syncthreads();

    const int wave = t >> 6, lane = t & 63;
    const int q = lane >> 4, mrow = lane & 15;

    f32x4 acc[NT];
#pragma unroll
    for (int i = 0; i < NT; i++) acc[i] = (f32x4){0.f, 0.f, 0.f, 0.f};

    const short8* wp8 = (const short8*)Wp;
#pragma unroll
    for (int kb = 0; kb < NKB; kb++) {
        short8 a = *(const short8*)&Xs[(wave * 16 + mrow) * RS + kb * 32 + q * 8];
#pragma unroll
        for (int tt = 0; tt < NT; tt++) {
            short8 b = wp8[(kb * NT + tt) * 64 + lane];   // coalesced dwordx4
            acc[tt] = __builtin_amdgcn_mfma_f32_16x16x32_bf16(a, b, acc[tt], 0, 0, 0);
        }
    }

    // Epilogue. C/D: col = lane&15 (tile tt), row = q*4 + reg.
#pragma unroll
    for (int tt = 0; tt < NT; tt++) {
        int nglob = tt * 16 + mrow;
        bool nside = (nglob < HOUT);
        int c = nside ? nglob : (nglob - HOUT);
        float bias = 0.f;
        if (nside) {
            if (bnA) bias += bnA[c];
            if (bnB) bias += bnB[c];
        } else if (bgA) {
            bias += bgA[c];
        }
#pragma unroll
        for (int r = 0; r < 4; r++) {
            int rr = row0 + wave * 16 + q * 4 + r;
            if (rr < n) {
                float o = acc[tt][r] + bias;
                if (nside) {
                    if (HNBF) Hnb[(size_t)rr * HOUT + c] = f2bf(o);
                    else      Hnf[(size_t)rr * HOUT + c] = o;
                } else {
                    Hgb[(size_t)rr * HOUT + c] = f2bf(o);
                }
            }
        }
    }
}

// K1: histrank (blocks [0,EB)) co-scheduled with layer-0 GEMM (blocks [EB,..)).
// The two are data-independent; atomic-latency waves overlap MFMA waves.
__global__ __launch_bounds__(256) void fused0_k(
    const int* __restrict__ rows, int* __restrict__ cntS, int* __restrict__ rank,
    const float* __restrict__ X, const unsigned short* __restrict__ Wp0,
    const float* __restrict__ bn0, const float* __restrict__ ab0, const float* __restrict__ bg0,
    unsigned short* __restrict__ Hn0b, unsigned short* __restrict__ Hgb, int n, int EB)
{
    if ((int)blockIdx.x < EB) {
        int c = blockIdx.x;
        int e = c * 256 + threadIdx.x;
        if (e < NEDGES) rank[e] = atomicAdd(&cntS[(c & 7) * NNODES + rows[e]], 1);
    } else {
        gemm_body<DIN, HID, false, false, true>(X, Wp0, bn0, ab0, bg0,
            nullptr, nullptr, nullptr, nullptr, Hn0b, Hgb, n, blockIdx.x - EB);
    }
}

template <int K, int HOUT, bool AFF, bool XBF, bool HNBF>
__global__ __launch_bounds__(256) void gemm_k(
    const void* __restrict__ X, const unsigned short* __restrict__ Wp,
    const float* __restrict__ bnA, const float* __restrict__ bnB, const float* __restrict__ bgA,
    const float* __restrict__ sums, const float* __restrict__ gamma, const float* __restrict__ beta,
    float* __restrict__ Hnf, unsigned short* __restrict__ Hnb, unsigned short* __restrict__ Hgb, int n)
{
    gemm_body<K, HOUT, AFF, XBF, HNBF>(X, Wp, bnA, bnB, bgA, sums, gamma, beta,
                                       Hnf, Hnb, Hgb, n, blockIdx.x);
}

// ---------------------------------------------------------------------------
// CSR: sumshard+scan1 merged; scan2; scan3; scatter+mark merged (atomic-free).
// ---------------------------------------------------------------------------

__global__ void sumscan_k(const int* __restrict__ cntS, int* __restrict__ base,
                          int* __restrict__ cnt, int* __restrict__ part, int n) {
    __shared__ int sm[256];
    int t = threadIdx.x, r = blockIdx.x * 256 + t;
    int c = 0;
    if (r < n) {
        int b[8];
#pragma unroll
        for (int s = 0; s < 8; s++) { b[s] = c; c += cntS[s * NNODES + r]; }
        cnt[r] = c;
        *(int4*)&base[r * 8]     = make_int4(b[0], b[1], b[2], b[3]);
        *(int4*)&base[r * 8 + 4] = make_int4(b[4], b[5], b[6], b[7]);
    }
    sm[t] = c;
    __syncthreads();
    for (int off = 128; off > 0; off >>= 1) {
        if (t < off) sm[t] += sm[t + off];
        __syncthreads();
    }
    if (t == 0) part[blockIdx.x] = sm[0];
}

__global__ void scan2_k(int* part, int nb) {
    __shared__ int s[512];
    int t = threadIdx.x;
    int v = (t < nb) ? part[t] : 0;
    s[t] = v;
    __syncthreads();
    for (int off = 1; off < 512; off <<= 1) {
        int a = (t >= off) ? s[t - off] : 0;
        __syncthreads();
        s[t] += a;
        __syncthreads();
    }
    if (t < nb) part[t] = s[t] - v;
}

__global__ void scan3_k(const int* __restrict__ cnt, const int* __restrict__ part,
                        int* __restrict__ rowptr, int n, int E) {
    __shared__ int s[256];
    int t = threadIdx.x;
    int i = blockIdx.x * 256 + t;
    int v = (i < n) ? cnt[i] : 0;
    s[t] = v;
    __syncthreads();
    for (int off = 1; off < 256; off <<= 1) {
        int a = (t >= off) ? s[t - off] : 0;
        __syncthreads();
        s[t] += a;
        __syncthreads();
    }
    if (i < n) rowptr[i] = part[blockIdx.x] + s[t] - v;
    if (i == 0) rowptr[n] = E;
}

__global__ void scattermark_k(const int* __restrict__ rows, const int* __restrict__ cols,
                              const float* __restrict__ vals, const int* __restrict__ rank,
                              const int* __restrict__ base, const int* __restrict__ rowptr,
                              int2* __restrict__ cs, const int* __restrict__ idx,
                              int* __restrict__ mark, int EB) {
    if ((int)blockIdx.x < EB) {
        int e = blockIdx.x * 256 + threadIdx.x;
        if (e < NEDGES) {
            int r = rows[e];
            int s = (e >> 8) & 7;               // matches fused0_k's shard choice
            cs[rowptr[r] + base[r * 8 + s] + rank[e]] = make_int2(cols[e], __float_as_int(vals[e]));
        }
    } else {
        int j = ((int)blockIdx.x - EB) * 256 + threadIdx.x;
        if (j < NIDX) mark[idx[j]] = 1;
    }
}

// ---------------------------------------------------------------------------
// SpMM (CSR gather): S[row] = Hn[row] + sum_e val[e]*Hg[col[e]], Hg bf16.
// SBF: S/Hn in bf16 (stats still from fp32 acc). MARKED: skip rows not in idx.
// ---------------------------------------------------------------------------

template <int HH, bool STATS, bool SBF, bool MARKED>
__global__ __launch_bounds__(256) void spmm_k(
    const int* __restrict__ rowptr, const int2* __restrict__ cs,
    const unsigned short* __restrict__ Hgb, void* __restrict__ Sv,
    float* __restrict__ stats, const int* __restrict__ mark, int n)
{
    constexpr int L  = HH / 4;
    constexpr int GP = 256 / L;
    const int lane = threadIdx.x % L;
    const int g = threadIdx.x / L;
    const int gid = blockIdx.x * GP + g;
    const int ngroups = gridDim.x * GP;
    const int c0 = lane * 4;

    float4 sum = make_float4(0.f, 0.f, 0.f, 0.f);
    float4 sq  = make_float4(0.f, 0.f, 0.f, 0.f);
    for (int row = gid; row < n; row += ngroups) {
        if (MARKED && !mark[row]) continue;
        int e0 = rowptr[row], e1 = rowptr[row + 1];
        float4 a0, a1 = make_float4(0.f, 0.f, 0.f, 0.f);
        if (SBF) {
            uint2 h = *(const uint2*)((const unsigned short*)Sv + (size_t)row * HH + c0);
            a0 = make_float4(bf2f_lo(h.x), bf2f_hi(h.x), bf2f_lo(h.y), bf2f_hi(h.y));
        } else {
            a0 = *(const float4*)((const float*)Sv + (size_t)row * HH + c0);
        }
        int e = e0;
        for (; e + 1 < e1; e += 2) {
            int2 p0 = cs[e], p1 = cs[e + 1];
            float v0 = __int_as_float(p0.y), v1 = __int_as_float(p1.y);
            uint2 h0 = *(const uint2*)&Hgb[(size_t)p0.x * HH + c0];
            uint2 h1 = *(const uint2*)&Hgb[(size_t)p1.x * HH + c0];
            a0.x += v0 * bf2f_lo(h0.x); a0.y += v0 * bf2f_hi(h0.x);
            a0.z += v0 * bf2f_lo(h0.y); a0.w += v0 * bf2f_hi(h0.y);
            a1.x += v1 * bf2f_lo(h1.x); a1.y += v1 * bf2f_hi(h1.x);
            a1.z += v1 * bf2f_lo(h1.y); a1.w += v1 * bf2f_hi(h1.y);
        }
        if (e < e1) {
            int2 p = cs[e];
            float v = __int_as_float(p.y);
            uint2 h = *(const uint2*)&Hgb[(size_t)p.x * HH + c0];
            a0.x += v * bf2f_lo(h.x); a0.y += v * bf2f_hi(h.x);
            a0.z += v * bf2f_lo(h.y); a0.w += v * bf2f_hi(h.y);
        }
        float4 acc = make_float4(a0.x + a1.x, a0.y + a1.y, a0.z + a1.z, a0.w + a1.w);
        if (SBF) {
            uint2 o;
            o.x = (unsigned)f2bf(acc.x) | ((unsigned)f2bf(acc.y) << 16);
            o.y = (unsigned)f2bf(acc.z) | ((unsigned)f2bf(acc.w) << 16);
            *(uint2*)((unsigned short*)Sv + (size_t)row * HH + c0) = o;
        } else {
            *(float4*)((float*)Sv + (size_t)row * HH + c0) = acc;
        }
        if (STATS) {
            sum.x += acc.x; sum.y += acc.y; sum.z += acc.z; sum.w += acc.w;
            sq.x += acc.x * acc.x; sq.y += acc.y * acc.y;
            sq.z += acc.z * acc.z; sq.w += acc.w * acc.w;
        }
    }

    if constexpr (STATS) {
        __shared__ float rs[GP][HH];
        __shared__ float rq[GP][HH];
        *(float4*)&rs[g][c0] = sum;
        *(float4*)&rq[g][c0] = sq;
        __syncthreads();
        if (threadIdx.x < HH) {
            float a = 0.f, b = 0.f;
            for (int w = 0; w < GP; w++) { a += rs[w][threadIdx.x]; b += rq[w][threadIdx.x]; }
            int stripe = blockIdx.x & 7;
            atomicAdd(&stats[stripe * 128 + threadIdx.x], a);
            atomicAdd(&stats[stripe * 128 + HH + threadIdx.x], b);
        }
    }
}

__global__ void gather_k(const float* __restrict__ S, const int* __restrict__ idx,
                         float* __restrict__ out, int total4) {
    int j = blockIdx.x * 256 + threadIdx.x;
    if (j < total4) {
        int r = j / (EMB / 4), c4 = (j % (EMB / 4)) * 4;
        *(float4*)&out[(size_t)j * 4] = *(const float4*)&S[(size_t)idx[r] * EMB + c4];
    }
}

// ---------------------------------------------------------------------------

extern "C" void kernel_launch(void* const* d_in, const int* in_sizes, int n_in,
                              void* d_out, int out_size, void* d_ws, size_t ws_size,
                              hipStream_t stream) {
    const float* features = (const float*)d_in[0];
    const int*   rows     = (const int*)d_in[1];
    const int*   cols     = (const int*)d_in[2];
    const float* vals     = (const float*)d_in[3];
    const int*   idx      = (const int*)d_in[4];
    const float* Wn0 = (const float*)d_in[5];
    const float* bn0 = (const float*)d_in[6];
    const float* Wg0 = (const float*)d_in[7];
    const float* bg0 = (const float*)d_in[8];
    const float* ab0 = (const float*)d_in[9];
    const float* g0  = (const float*)d_in[10];
    const float* b0  = (const float*)d_in[11];
    const float* Wn1 = (const float*)d_in[12];
    const float* Wg1 = (const float*)d_in[13];
    const float* ab1 = (const float*)d_in[14];
    const float* g1  = (const float*)d_in[15];
    const float* b1  = (const float*)d_in[16];
    const float* WnL = (const float*)d_in[17];
    const float* WgL = (const float*)d_in[18];
    const float* abL = (const float*)d_in[19];
    float* out = (float*)d_out;

    // Workspace layout (~69 MB), all sub-buffers 16B-aligned.
    float*          HnLf = (float*)d_ws;                        // 100k x 32 fp32 (HnL/SL)
    unsigned short* nA   = (unsigned short*)(HnLf + (size_t)NNODES * EMB); // Hn0/S0 bf16
    unsigned short* nB   = nA + (size_t)NNODES * HID;           // Hn1/S1 bf16
    unsigned short* Hgb  = nB + (size_t)NNODES * HID;           // Hg (all layers) bf16
    int*   part   = (int*)(Hgb + (size_t)NNODES * HID);         // 1024
    int*   rowptr = part + 1024;                                // N+4
    int*   cnt    = rowptr + (NNODES + 4);                      // N
    int*   rank   = cnt + NNODES;                               // E
    int*   base   = rank + NEDGES;                              // 8N
    int2*  cs     = (int2*)(base + 8 * NNODES);                 // E
    unsigned short* Wp0 = (unsigned short*)(cs + NEDGES);       // 16384
    unsigned short* Wp1 = Wp0 + 16384;                          // 8192
    unsigned short* WpL = Wp1 + 8192;                           // 4096
    // ---- single zeroed region: cntS | stats | mark ----
    int*   cntS  = (int*)(WpL + 4096);                          // 8N
    float* stats = (float*)(cntS + 8 * NNODES);                 // 2304
    int*   mark  = (int*)(stats + 2304);                        // N
    float* sums0 = stats;
    float* sums1 = stats + 1024;
    size_t zbytes = (size_t)8 * NNODES * 4 + 2304 * 4 + (size_t)NNODES * 4;

    hipMemsetAsync(cntS, 0, zbytes, stream);

    const int EB  = (NEDGES + 255) / 256;   // 3125 edge chunks
    const int NB  = (NNODES + 255) / 256;   // 391
    const int GBm = (NNODES + 63) / 64;     // 1563
    const int MB  = (NIDX + 255) / 256;     // 196

    packall_k<<<112, 256, 0, stream>>>(Wn0, Wg0, Wn1, Wg1, WnL, WgL, Wp0, Wp1, WpL);

    // K1: histrank + layer-0 dual GEMM, co-scheduled (independent subsystems).
    fused0_k<<<EB + GBm, 256, 0, stream>>>(rows, cntS, rank, features, Wp0,
                                           bn0, ab0, bg0, nA, Hgb, NNODES, EB);

    sumscan_k<<<NB, 256, 0, stream>>>(cntS, base, cnt, part, NNODES);
    scan2_k<<<1, 512, 0, stream>>>(part, NB);
    scan3_k<<<NB, 256, 0, stream>>>(cnt, part, rowptr, NNODES, NEDGES);
    scattermark_k<<<EB + MB, 256, 0, stream>>>(rows, cols, vals, rank, base, rowptr,
                                               cs, idx, mark, EB);

    // Layer 0 aggregate: S0 = Hn0 + A@Hg0 (bf16 in/out, stats fp32)
    spmm_k<HID, true, true, false><<<1600, 256, 0, stream>>>(rowptr, cs, Hgb, nA, sums0, nullptr, NNODES);

    // Layer 1: BN finalize folded into gemm; S1 = Hn1 + ab1 + A@Hg1
    gemm_k<HID, HID, true, true, true><<<GBm, 256, 0, stream>>>(
        nA, Wp1, ab1, nullptr, nullptr, sums0, g0, b0, nullptr, nB, Hgb, NNODES);
    spmm_k<HID, true, true, false><<<1600, 256, 0, stream>>>(rowptr, cs, Hgb, nB, sums1, nullptr, NNODES);

    // Last layer: HnL fp32, HgL bf16; SpMM only for rows referenced by idx.
    gemm_k<HID, EMB, true, true, false><<<GBm, 256, 0, stream>>>(
        nB, WpL, abL, nullptr, nullptr, sums1, g1, b1, HnLf, nullptr, Hgb, NNODES);
    spmm_k<EMB, false, false, true><<<1600, 256, 0, stream>>>(rowptr, cs, Hgb, HnLf, nullptr, mark, NNODES);

    gather_k<<<(NIDX * EMB / 4 + 255) / 256, 256, 0, stream>>>(HnLf, idx, out, NIDX * EMB / 4);
}

// Round 8
// 287.204 us; speedup vs baseline: 3.0852x; 1.0946x over previous
//
#include <hip/hip_runtime.h>

// Problem constants (fixed by the reference).
#define NNODES 100000
#define NEDGES 800000
#define DIN    128
#define HID    64
#define EMB    32
#define NIDX   50000
#define BN_EPS 1e-5f

#define NCHK 256                 // edge chunks (partition blocks)
#define EC   (NEDGES / NCHK)     // 3125 edges per chunk (exact)
#define NB   ((NNODES + 63) / 64)// 1563 row-buckets of 64 rows

typedef __attribute__((ext_vector_type(8))) short short8;   // 8 bf16 = 4 VGPR
typedef __attribute__((ext_vector_type(4))) float f32x4;    // MFMA C/D

__device__ inline unsigned short f2bf(float f) {            // RNE, matches HW
    unsigned u = __float_as_uint(f);
    unsigned r = u + 0x7FFFu + ((u >> 16) & 1u);
    return (unsigned short)(r >> 16);
}
__device__ inline float bf2f_lo(unsigned u) { return __uint_as_float(u << 16); }
__device__ inline float bf2f_hi(unsigned u) { return __uint_as_float(u & 0xffff0000u); }

// ---------------------------------------------------------------------------
// W pre-pack (all three layers): fp32 [Wn|Wg] -> bf16 B-fragment-major.
// ---------------------------------------------------------------------------

__device__ inline void pack_seg(const float* __restrict__ Wn, const float* __restrict__ Wg,
                                unsigned short* __restrict__ Wp, int HOUT, int l2nt, int f) {
    int j = f & 7, lane = (f >> 3) & 63, g = f >> 9;
    int tt = g & ((1 << l2nt) - 1), kb = g >> l2nt;
    int k = kb * 32 + ((lane >> 4) * 8) + j;
    int nn = tt * 16 + (lane & 15);
    float v = (nn < HOUT) ? Wn[k * HOUT + nn] : Wg[k * HOUT + (nn - HOUT)];
    Wp[f] = f2bf(v);
}

__global__ void packall_k(const float* Wn0, const float* Wg0, const float* Wn1,
                          const float* Wg1, const float* WnL, const float* WgL,
                          unsigned short* Wp0, unsigned short* Wp1, unsigned short* WpL) {
    int f = blockIdx.x * 256 + threadIdx.x;
    if (f < 16384)      pack_seg(Wn0, Wg0, Wp0, 64, 3, f);           // 128x128
    else if (f < 24576) pack_seg(Wn1, Wg1, Wp1, 64, 3, f - 16384);   // 64x128
    else if (f < 28672) pack_seg(WnL, WgL, WpL, 32, 2, f - 24576);   // 64x64
}

// ---------------------------------------------------------------------------
// CSR build, atomic-free (LDS atomics only; no device-scope atomic RMW --
// round 7 measured 800k atomic-returns pinned at 5.7/cycle = 58 us).
// ---------------------------------------------------------------------------

// K_A: blocks [0,NCHK): LDS 1563-bin histogram of bucket=row>>6 for chunk.
//      blocks [NCHK,..): mark[idx[j]] = 1.
__global__ __launch_bounds__(256) void bhist_k(const int* __restrict__ rows,
                                               int* __restrict__ Bcnt,
                                               const int* __restrict__ idx,
                                               int* __restrict__ mark) {
    if ((int)blockIdx.x >= NCHK) {
        int j = ((int)blockIdx.x - NCHK) * 256 + threadIdx.x;
        if (j < NIDX) mark[idx[j]] = 1;
        return;
    }
    __shared__ int hist[NB];
    int t = threadIdx.x, blk = blockIdx.x;
    for (int b = t; b < NB; b += 256) hist[b] = 0;
    __syncthreads();
    for (int i = t; i < EC; i += 256)
        atomicAdd(&hist[rows[blk * EC + i] >> 6], 1);
    __syncthreads();
    for (int b = t; b < NB; b += 256) Bcnt[b * NCHK + blk] = hist[b];
}

// K_B1: per-bucket exclusive prefix over chunks; transposed copy for K_C;
//       bucket totals.
__global__ void bprefix_k(const int* __restrict__ Bcnt, int* __restrict__ BcntT,
                          int* __restrict__ bTot) {
    int b = blockIdx.x * 256 + threadIdx.x;
    if (b >= NB) return;
    int run = 0;
    for (int j = 0; j < NCHK; j++) {
        BcntT[j * NB + b] = run;        // exclusive prefix for chunk j
        run += Bcnt[b * NCHK + j];
    }
    bTot[b] = run;
}

// K_B2: exclusive scan of 1563 bucket totals -> bBase.
__global__ void bscan_k(const int* __restrict__ bTot, int* __restrict__ bBase) {
    __shared__ int s[256];
    int t = threadIdx.x;
    int v[7], loc = 0;
#pragma unroll
    for (int i = 0; i < 7; i++) {
        int ix = t * 7 + i;
        v[i] = loc;                      // thread-local exclusive prefix
        loc += (ix < NB) ? bTot[ix] : 0;
    }
    s[t] = loc;
    __syncthreads();
    for (int off = 1; off < 256; off <<= 1) {
        int a = (t >= off) ? s[t - off] : 0;
        __syncthreads();
        s[t] += a;
        __syncthreads();
    }
    int base = s[t] - loc;               // exclusive across threads
#pragma unroll
    for (int i = 0; i < 7; i++) {
        int ix = t * 7 + i;
        if (ix < NB) bBase[ix] = base + v[i];
    }
    if (t == 255) bBase[NB] = NEDGES;
}

// K_D: one block per bucket (64 rows, ~512 edges): LDS 64-bin hist + scan ->
//      rowptr; scatter {col,val} into final cs.
__global__ __launch_bounds__(256) void bfinal_k(const int4* __restrict__ ebuf,
                                                const int* __restrict__ bBase,
                                                int* __restrict__ rowptr,
                                                int2* __restrict__ cs) {
    __shared__ int hist[64], sc[64], cur[64];
    int b = blockIdx.x, t = threadIdx.x;
    int e0 = bBase[b], e1 = bBase[b + 1];
    int r0 = b << 6;
    if (t < 64) hist[t] = 0;
    __syncthreads();
    for (int i = e0 + t; i < e1; i += 256)
        atomicAdd(&hist[ebuf[i].x & 63], 1);
    __syncthreads();
    if (t == 0) {
        int run = e0;
        for (int j = 0; j < 64; j++) { sc[j] = run; run += hist[j]; }
    }
    __syncthreads();
    if (t < 64) {
        cur[t] = sc[t];
        int r = r0 + t;
        if (r < NNODES) rowptr[r] = sc[t];
    }
    if (b == NB - 1 && t == 0) rowptr[NNODES] = NEDGES;
    __syncthreads();
    for (int i = e0 + t; i < e1; i += 256) {
        int4 v = ebuf[i];
        int p = atomicAdd(&cur[v.x & 63], 1);
        cs[p] = make_int2(v.y, v.z);
    }
}

// ---------------------------------------------------------------------------
// MFMA dual-GEMM body. [Hn | Hg] = act(X) @ [Wn | Wg] (+ per-col biases);
// Hg always bf16 out; Hn bf16 (HNBF) or fp32. X fp32 or bf16 (XBF).
// AFF: BN scale/shift recomputed in-block from striped sums.
// ---------------------------------------------------------------------------

template <int K, int HOUT, bool AFF, bool XBF, bool HNBF>
__device__ void gemm_body(const void* __restrict__ Xv, const unsigned short* __restrict__ Wp,
                          const float* __restrict__ bnA, const float* __restrict__ bnB,
                          const float* __restrict__ bgA,
                          const float* __restrict__ sums, const float* __restrict__ gamma,
                          const float* __restrict__ beta,
                          float* __restrict__ Hnf, unsigned short* __restrict__ Hnb,
                          unsigned short* __restrict__ Hgb, int n, int blk)
{
    constexpr int NT = 2 * HOUT / 16, NKB = K / 32;
    constexpr int RS = K + 8;
    __shared__ unsigned short Xs[64 * RS];
    __shared__ float sSc[64], sSh[64];

    const int row0 = blk * 64;
    const int t = threadIdx.x;

    if (AFF) {               // in-block BN finalize: 1KB of reads, once per block
        if (t < 64) {
            float sum = 0.f, sq = 0.f;
#pragma unroll
            for (int s = 0; s < 8; s++) { sum += sums[s * 128 + t]; sq += sums[s * 128 + 64 + t]; }
            float m = sum / (float)NNODES;
            float var = sq / (float)NNODES - m * m;
            float sc = gamma[t] * rsqrtf(var + BN_EPS);
            sSc[t] = sc; sSh[t] = beta[t] - m * sc;
        }
        __syncthreads();
    }

    // Stage 64 x K -> bf16 LDS, 8 k-cols per step (affine+relu on the fly).
    for (int li = t; li < 64 * K / 8; li += 256) {
        int r  = li / (K / 8);
        int k8 = (li % (K / 8)) * 8;
        int rr = row0 + r;
        float v[8];
        if (XBF) {
            uint4 u = (rr < n) ? *(const uint4*)((const unsigned short*)Xv + (size_t)rr * K + k8)
                               : make_uint4(0, 0, 0, 0);
            v[0] = bf2f_lo(u.x); v[1] = bf2f_hi(u.x);
            v[2] = bf2f_lo(u.y); v[3] = bf2f_hi(u.y);
            v[4] = bf2f_lo(u.z); v[5] = bf2f_hi(u.z);
            v[6] = bf2f_lo(u.w); v[7] = bf2f_hi(u.w);
        } else {
            const float* Xf = (const float*)Xv;
            float4 a = make_float4(0.f, 0.f, 0.f, 0.f), b = a;
            if (rr < n) {
                a = *(const float4*)&Xf[(size_t)rr * K + k8];
                b = *(const float4*)&Xf[(size_t)rr * K + k8 + 4];
            }
            v[0] = a.x; v[1] = a.y; v[2] = a.z; v[3] = a.w;
            v[4] = b.x; v[5] = b.y; v[6] = b.z; v[7] = b.w;
        }
        if (AFF) {
#pragma unroll
            for (int i = 0; i < 8; i++) v[i] = fmaxf(v[i] * sSc[k8 + i] + sSh[k8 + i], 0.f);
        }
        uint4 o;
        o.x = (unsigned)f2bf(v[0]) | ((unsigned)f2bf(v[1]) << 16);
        o.y = (unsigned)f2bf(v[2]) | ((unsigned)f2bf(v[3]) << 16);
        o.z = (unsigned)f2bf(v[4]) | ((unsigned)f2bf(v[5]) << 16);
        o.w = (unsigned)f2bf(v[6]) | ((unsigned)f2bf(v[7]) << 16);
        *(uint4*)&Xs[r * RS + k8] = o;
    }
    __syncthreads();

    const int wave = t >> 6, lane = t & 63;
    const int q = lane >> 4, mrow = lane & 15;

    f32x4 acc[NT];
#pragma unroll
    for (int i = 0; i < NT; i++) acc[i] = (f32x4){0.f, 0.f, 0.f, 0.f};

    const short8* wp8 = (const short8*)Wp;
#pragma unroll
    for (int kb = 0; kb < NKB; kb++) {
        short8 a = *(const short8*)&Xs[(wave * 16 + mrow) * RS + kb * 32 + q * 8];
#pragma unroll
        for (int tt = 0; tt < NT; tt++) {
            short8 b = wp8[(kb * NT + tt) * 64 + lane];   // coalesced dwordx4
            acc[tt] = __builtin_amdgcn_mfma_f32_16x16x32_bf16(a, b, acc[tt], 0, 0, 0);
        }
    }

    // Epilogue. C/D: col = lane&15 (tile tt), row = q*4 + reg.
#pragma unroll
    for (int tt = 0; tt < NT; tt++) {
        int nglob = tt * 16 + mrow;
        bool nside = (nglob < HOUT);
        int c = nside ? nglob : (nglob - HOUT);
        float bias = 0.f;
        if (nside) {
            if (bnA) bias += bnA[c];
            if (bnB) bias += bnB[c];
        } else if (bgA) {
            bias += bgA[c];
        }
#pragma unroll
        for (int r = 0; r < 4; r++) {
            int rr = row0 + wave * 16 + q * 4 + r;
            if (rr < n) {
                float o = acc[tt][r] + bias;
                if (nside) {
                    if (HNBF) Hnb[(size_t)rr * HOUT + c] = f2bf(o);
                    else      Hnf[(size_t)rr * HOUT + c] = o;
                } else {
                    Hgb[(size_t)rr * HOUT + c] = f2bf(o);
                }
            }
        }
    }
}

// K_C: blocks [0,NCHK): bucket-partition chunk edges via LDS cursors
//      (atomic-free globally); blocks [NCHK,..): layer-0 dual GEMM.
//      The two are data-independent and co-schedule (round-7 trick).
__global__ __launch_bounds__(256) void part_gemm0_k(
    const int* __restrict__ rows, const int* __restrict__ cols,
    const float* __restrict__ vals, const int* __restrict__ BcntT,
    const int* __restrict__ bBase, int4* __restrict__ ebuf,
    const float* __restrict__ X, const unsigned short* __restrict__ Wp0,
    const float* __restrict__ bn0, const float* __restrict__ ab0, const float* __restrict__ bg0,
    unsigned short* __restrict__ Hn0b, unsigned short* __restrict__ Hgb, int n)
{
    if ((int)blockIdx.x < NCHK) {
        __shared__ int cur[NB];
        int t = threadIdx.x, blk = blockIdx.x;
        for (int b = t; b < NB; b += 256) cur[b] = bBase[b] + BcntT[blk * NB + b];
        __syncthreads();
        for (int i = t; i < EC; i += 256) {
            int e = blk * EC + i;
            int r = rows[e];
            int p = atomicAdd(&cur[r >> 6], 1);   // LDS atomic
            ebuf[p] = make_int4(r, cols[e], __float_as_int(vals[e]), 0);
        }
    } else {
        gemm_body<DIN, HID, false, false, true>(X, Wp0, bn0, ab0, bg0,
            nullptr, nullptr, nullptr, nullptr, Hn0b, Hgb, n, blockIdx.x - NCHK);
    }
}

template <int K, int HOUT, bool AFF, bool XBF, bool HNBF>
__global__ __launch_bounds__(256) void gemm_k(
    const void* __restrict__ X, const unsigned short* __restrict__ Wp,
    const float* __restrict__ bnA, const float* __restrict__ bnB, const float* __restrict__ bgA,
    const float* __restrict__ sums, const float* __restrict__ gamma, const float* __restrict__ beta,
    float* __restrict__ Hnf, unsigned short* __restrict__ Hnb, unsigned short* __restrict__ Hgb, int n)
{
    gemm_body<K, HOUT, AFF, XBF, HNBF>(X, Wp, bnA, bnB, bgA, sums, gamma, beta,
                                       Hnf, Hnb, Hgb, n, blockIdx.x);
}

// ---------------------------------------------------------------------------
// SpMM (CSR gather): S[row] = Hn[row] + sum_e val[e]*Hg[col[e]], Hg bf16.
// SBF: S/Hn in bf16 (stats still from fp32 acc). MARKED: skip rows not in idx.
// ---------------------------------------------------------------------------

template <int HH, bool STATS, bool SBF, bool MARKED>
__global__ __launch_bounds__(256) void spmm_k(
    const int* __restrict__ rowptr, const int2* __restrict__ cs,
    const unsigned short* __restrict__ Hgb, void* __restrict__ Sv,
    float* __restrict__ stats, const int* __restrict__ mark, int n)
{
    constexpr int L  = HH / 4;
    constexpr int GP = 256 / L;
    const int lane = threadIdx.x % L;
    const int g = threadIdx.x / L;
    const int gid = blockIdx.x * GP + g;
    const int ngroups = gridDim.x * GP;
    const int c0 = lane * 4;

    float4 sum = make_float4(0.f, 0.f, 0.f, 0.f);
    float4 sq  = make_float4(0.f, 0.f, 0.f, 0.f);
    for (int row = gid; row < n; row += ngroups) {
        if (MARKED && !mark[row]) continue;
        int e0 = rowptr[row], e1 = rowptr[row + 1];
        float4 a0, a1 = make_float4(0.f, 0.f, 0.f, 0.f);
        if (SBF) {
            uint2 h = *(const uint2*)((const unsigned short*)Sv + (size_t)row * HH + c0);
            a0 = make_float4(bf2f_lo(h.x), bf2f_hi(h.x), bf2f_lo(h.y), bf2f_hi(h.y));
        } else {
            a0 = *(const float4*)((const float*)Sv + (size_t)row * HH + c0);
        }
        int e = e0;
        for (; e + 1 < e1; e += 2) {
            int2 p0 = cs[e], p1 = cs[e + 1];
            float v0 = __int_as_float(p0.y), v1 = __int_as_float(p1.y);
            uint2 h0 = *(const uint2*)&Hgb[(size_t)p0.x * HH + c0];
            uint2 h1 = *(const uint2*)&Hgb[(size_t)p1.x * HH + c0];
            a0.x += v0 * bf2f_lo(h0.x); a0.y += v0 * bf2f_hi(h0.x);
            a0.z += v0 * bf2f_lo(h0.y); a0.w += v0 * bf2f_hi(h0.y);
            a1.x += v1 * bf2f_lo(h1.x); a1.y += v1 * bf2f_hi(h1.x);
            a1.z += v1 * bf2f_lo(h1.y); a1.w += v1 * bf2f_hi(h1.y);
        }
        if (e < e1) {
            int2 p = cs[e];
            float v = __int_as_float(p.y);
            uint2 h = *(const uint2*)&Hgb[(size_t)p.x * HH + c0];
            a0.x += v * bf2f_lo(h.x); a0.y += v * bf2f_hi(h.x);
            a0.z += v * bf2f_lo(h.y); a0.w += v * bf2f_hi(h.y);
        }
        float4 acc = make_float4(a0.x + a1.x, a0.y + a1.y, a0.z + a1.z, a0.w + a1.w);
        if (SBF) {
            uint2 o;
            o.x = (unsigned)f2bf(acc.x) | ((unsigned)f2bf(acc.y) << 16);
            o.y = (unsigned)f2bf(acc.z) | ((unsigned)f2bf(acc.w) << 16);
            *(uint2*)((unsigned short*)Sv + (size_t)row * HH + c0) = o;
        } else {
            *(float4*)((float*)Sv + (size_t)row * HH + c0) = acc;
        }
        if (STATS) {
            sum.x += acc.x; sum.y += acc.y; sum.z += acc.z; sum.w += acc.w;
            sq.x += acc.x * acc.x; sq.y += acc.y * acc.y;
            sq.z += acc.z * acc.z; sq.w += acc.w * acc.w;
        }
    }

    if constexpr (STATS) {
        __shared__ float rs[GP][HH];
        __shared__ float rq[GP][HH];
        *(float4*)&rs[g][c0] = sum;
        *(float4*)&rq[g][c0] = sq;
        __syncthreads();
        if (threadIdx.x < HH) {
            float a = 0.f, b = 0.f;
            for (int w = 0; w < GP; w++) { a += rs[w][threadIdx.x]; b += rq[w][threadIdx.x]; }
            int stripe = blockIdx.x & 7;
            atomicAdd(&stats[stripe * 128 + threadIdx.x], a);
            atomicAdd(&stats[stripe * 128 + HH + threadIdx.x], b);
        }
    }
}

__global__ void gather_k(const float* __restrict__ S, const int* __restrict__ idx,
                         float* __restrict__ out, int total4) {
    int j = blockIdx.x * 256 + threadIdx.x;
    if (j < total4) {
        int r = j / (EMB / 4), c4 = (j % (EMB / 4)) * 4;
        *(float4*)&out[(size_t)j * 4] = *(const float4*)&S[(size_t)idx[r] * EMB + c4];
    }
}

// ---------------------------------------------------------------------------

extern "C" void kernel_launch(void* const* d_in, const int* in_sizes, int n_in,
                              void* d_out, int out_size, void* d_ws, size_t ws_size,
                              hipStream_t stream) {
    const float* features = (const float*)d_in[0];
    const int*   rows     = (const int*)d_in[1];
    const int*   cols     = (const int*)d_in[2];
    const float* vals     = (const float*)d_in[3];
    const int*   idx      = (const int*)d_in[4];
    const float* Wn0 = (const float*)d_in[5];
    const float* bn0 = (const float*)d_in[6];
    const float* Wg0 = (const float*)d_in[7];
    const float* bg0 = (const float*)d_in[8];
    const float* ab0 = (const float*)d_in[9];
    const float* g0  = (const float*)d_in[10];
    const float* b0  = (const float*)d_in[11];
    const float* Wn1 = (const float*)d_in[12];
    const float* Wg1 = (const float*)d_in[13];
    const float* ab1 = (const float*)d_in[14];
    const float* g1  = (const float*)d_in[15];
    const float* b1  = (const float*)d_in[16];
    const float* WnL = (const float*)d_in[17];
    const float* WgL = (const float*)d_in[18];
    const float* abL = (const float*)d_in[19];
    float* out = (float*)d_out;

    // Workspace layout (~72 MB), 16B-aligned sub-buffers.
    float*          HnLf = (float*)d_ws;                        // N x EMB fp32 (HnL/SL)
    unsigned short* nA   = (unsigned short*)(HnLf + (size_t)NNODES * EMB); // Hn0/S0 bf16
    unsigned short* nB   = nA + (size_t)NNODES * HID;           // Hn1/S1 bf16
    unsigned short* Hgb  = nB + (size_t)NNODES * HID;           // Hg (all layers) bf16
    int4*  ebuf  = (int4*)(Hgb + (size_t)NNODES * HID);         // E  (bucket-partitioned edges)
    int2*  cs    = (int2*)(ebuf + NEDGES);                      // E  (final CSR payload)
    int*   rowptr = (int*)(cs + NEDGES);                        // N+4
    int*   Bcnt  = rowptr + (NNODES + 4);                       // NB*NCHK
    int*   BcntT = Bcnt + NB * NCHK;                            // NCHK*NB
    int*   bTot  = BcntT + NCHK * NB;                           // NB (pad 1568)
    int*   bBase = bTot + 1568;                                 // NB+1 (pad 1568)
    unsigned short* Wp0 = (unsigned short*)(bBase + 1568);      // 16384
    unsigned short* Wp1 = Wp0 + 16384;                          // 8192
    unsigned short* WpL = Wp1 + 8192;                           // 4096
    // ---- single zeroed region: stats | mark ----
    float* stats = (float*)(WpL + 4096);                        // 2304
    int*   mark  = (int*)(stats + 2304);                        // N
    float* sums0 = stats;
    float* sums1 = stats + 1024;
    size_t zbytes = 2304 * 4 + (size_t)NNODES * 4;

    hipMemsetAsync(stats, 0, zbytes, stream);

    const int GBm = (NNODES + 63) / 64;     // 1563
    const int MB  = (NIDX + 255) / 256;     // 196

    packall_k<<<112, 256, 0, stream>>>(Wn0, Wg0, Wn1, Wg1, WnL, WgL, Wp0, Wp1, WpL);

    // CSR build (atomic-free) -------------------------------------------------
    bhist_k<<<NCHK + MB, 256, 0, stream>>>(rows, Bcnt, idx, mark);
    bprefix_k<<<7, 256, 0, stream>>>(Bcnt, BcntT, bTot);
    bscan_k<<<1, 256, 0, stream>>>(bTot, bBase);
    // partition (blocks [0,256)) co-scheduled with layer-0 dual GEMM
    part_gemm0_k<<<NCHK + GBm, 256, 0, stream>>>(rows, cols, vals, BcntT, bBase, ebuf,
                                                 features, Wp0, bn0, ab0, bg0,
                                                 nA, Hgb, NNODES);
    bfinal_k<<<NB, 256, 0, stream>>>(ebuf, bBase, rowptr, cs);

    // Layer 0 aggregate: S0 = Hn0 + A@Hg0 (bf16 in/out, stats fp32)
    spmm_k<HID, true, true, false><<<1600, 256, 0, stream>>>(rowptr, cs, Hgb, nA, sums0, nullptr, NNODES);

    // Layer 1: BN finalize folded into gemm; S1 = Hn1 + ab1 + A@Hg1
    gemm_k<HID, HID, true, true, true><<<GBm, 256, 0, stream>>>(
        nA, Wp1, ab1, nullptr, nullptr, sums0, g0, b0, nullptr, nB, Hgb, NNODES);
    spmm_k<HID, true, true, false><<<1600, 256, 0, stream>>>(rowptr, cs, Hgb, nB, sums1, nullptr, NNODES);

    // Last layer: HnL fp32, HgL bf16; SpMM only for rows referenced by idx.
    gemm_k<HID, EMB, true, true, false><<<GBm, 256, 0, stream>>>(
        nB, WpL, abL, nullptr, nullptr, sums1, g1, b1, HnLf, nullptr, Hgb, NNODES);
    spmm_k<EMB, false, false, true><<<1600, 256, 0, stream>>>(rowptr, cs, Hgb, HnLf, nullptr, mark, NNODES);

    gather_k<<<(NIDX * EMB / 4 + 255) / 256, 256, 0, stream>>>(HnLf, idx, out, NIDX * EMB / 4);
}